// Round 1
// baseline (3536.082 us; speedup 1.0000x reference)
//
#include <hip/hip_runtime.h>

#define N_NODES 50000
#define N_EDGES 600000
#define ETOT    650000   // N_EDGES + N_NODES self loops
#define EPS     1e-5f

static __device__ __forceinline__ float leaky(float v) { return v >= 0.f ? v : 0.2f * v; }

// ---------------------------------------------------------------------------
// Tiled fp32 GEMM: C[M,N] = A[M,K] @ B[K,N].  64x64 tile, 256 threads, 4x4/thread.
// Requires N % 64 == 0, K % 32 == 0 (true for all 4 GEMMs here). M guarded.
// ---------------------------------------------------------------------------
__global__ __launch_bounds__(256) void gemm_f32(
    const float* __restrict__ A, const float* __restrict__ B, float* __restrict__ C,
    int M, int N, int K) {
  __shared__ float As[32][68];   // transposed A tile, padded (row = 272B, 16B-aligned)
  __shared__ float Bs[32][64];
  const int tid = threadIdx.x;
  const int tx = tid & 15, ty = tid >> 4;
  const int m0 = blockIdx.x * 64, n0 = blockIdx.y * 64;
  float acc[4][4] = {};
  for (int k0 = 0; k0 < K; k0 += 32) {
#pragma unroll
    for (int i = 0; i < 8; ++i) {
      int idx = tid + i * 256;           // 0..2047
      int m = idx >> 5, k = idx & 31;
      int gm = m0 + m;
      As[k][m] = (gm < M) ? A[(size_t)gm * K + k0 + k] : 0.f;
    }
#pragma unroll
    for (int i = 0; i < 8; ++i) {
      int idx = tid + i * 256;
      int k = idx >> 6, n = idx & 63;
      Bs[k][n] = B[(size_t)(k0 + k) * N + n0 + n];
    }
    __syncthreads();
#pragma unroll
    for (int k = 0; k < 32; ++k) {
      float a0 = As[k][ty * 4 + 0], a1 = As[k][ty * 4 + 1];
      float a2 = As[k][ty * 4 + 2], a3 = As[k][ty * 4 + 3];
      float b0 = Bs[k][tx * 4 + 0], b1 = Bs[k][tx * 4 + 1];
      float b2 = Bs[k][tx * 4 + 2], b3 = Bs[k][tx * 4 + 3];
      acc[0][0] += a0 * b0; acc[0][1] += a0 * b1; acc[0][2] += a0 * b2; acc[0][3] += a0 * b3;
      acc[1][0] += a1 * b0; acc[1][1] += a1 * b1; acc[1][2] += a1 * b2; acc[1][3] += a1 * b3;
      acc[2][0] += a2 * b0; acc[2][1] += a2 * b1; acc[2][2] += a2 * b2; acc[2][3] += a2 * b3;
      acc[3][0] += a3 * b0; acc[3][1] += a3 * b1; acc[3][2] += a3 * b2; acc[3][3] += a3 * b3;
    }
    __syncthreads();
  }
#pragma unroll
  for (int i = 0; i < 4; ++i) {
    int gm = m0 + ty * 4 + i;
    if (gm < M) {
#pragma unroll
      for (int j = 0; j < 4; ++j) C[(size_t)gm * N + n0 + tx * 4 + j] = acc[i][j];
    }
  }
}

// ---------------------------------------------------------------------------
// Per-node attention scores: ssrc[i,h] = sum_c h[i,h*64+c]*a_src[h,c], same for dst.
// One wave per row; lanes cover 256 cols as float4; 16-lane group = one head.
// ---------------------------------------------------------------------------
__global__ __launch_bounds__(256) void attn_scores(
    const float* __restrict__ h, const float* __restrict__ a_src,
    const float* __restrict__ a_dst, float* __restrict__ ssrc, float* __restrict__ sdst) {
  const int wave = threadIdx.x >> 6, lane = threadIdx.x & 63;
  const int row = blockIdx.x * 4 + wave;
  if (row >= N_NODES) return;
  const float4 hv = *(const float4*)(h + (size_t)row * 256 + lane * 4);
  const float4 as = *(const float4*)(a_src + lane * 4);
  const float4 ad = *(const float4*)(a_dst + lane * 4);
  float ps = hv.x * as.x + hv.y * as.y + hv.z * as.z + hv.w * as.w;
  float pd = hv.x * ad.x + hv.y * ad.y + hv.z * ad.z + hv.w * ad.w;
#pragma unroll
  for (int off = 1; off < 16; off <<= 1) {
    ps += __shfl_xor(ps, off);
    pd += __shfl_xor(pd, off);
  }
  if ((lane & 15) == 0) {
    int hh = lane >> 4;
    ssrc[row * 4 + hh] = ps;
    sdst[row * 4 + hh] = pd;
  }
}

// degree count over all edges incl. self loops (deg buffer pre-zeroed)
__global__ __launch_bounds__(256) void deg_count(const int* __restrict__ ei, float* __restrict__ deg) {
  int e = blockIdx.x * 256 + threadIdx.x;
  if (e >= ETOT) return;
  int dst = (e < N_EDGES) ? ei[N_EDGES + e] : (e - N_EDGES);
  atomicAdd(&deg[dst], 1.0f);
}

__global__ __launch_bounds__(256) void dinv_k(float* __restrict__ deg) {
  int i = blockIdx.x * 256 + threadIdx.x;
  if (i < N_NODES) deg[i] = rsqrtf(fmaxf(deg[i], 1.0f));
}

static __device__ __forceinline__ void edge_sd(const int* ei, int e, int& src, int& dst) {
  if (e < N_EDGES) { src = ei[e]; dst = ei[N_EDGES + e]; }
  else             { src = dst = e - N_EDGES; }
}

// segment max of leaky(e) per (dst, head) via monotone-uint atomicMax
__global__ __launch_bounds__(256) void seg_max_k(
    const int* __restrict__ ei, const float* __restrict__ ssrc,
    const float* __restrict__ sdst, unsigned* __restrict__ menc) {
  int e = blockIdx.x * 256 + threadIdx.x;
  if (e >= ETOT) return;
  int src, dst; edge_sd(ei, e, src, dst);
#pragma unroll
  for (int h = 0; h < 4; ++h) {
    float v = leaky(ssrc[src * 4 + h] + sdst[dst * 4 + h]);
    unsigned b = __float_as_uint(v);
    unsigned enc = (b & 0x80000000u) ? ~b : (b | 0x80000000u);
    atomicMax(&menc[dst * 4 + h], enc);
  }
}

// decode monotone-uint back to float bits, in place
__global__ __launch_bounds__(256) void decode_k(unsigned* __restrict__ m, int n) {
  int i = blockIdx.x * 256 + threadIdx.x;
  if (i < n) {
    unsigned e = m[i];
    m[i] = (e & 0x80000000u) ? (e & 0x7FFFFFFFu) : ~e;
  }
}

// segment sum of exp(e - m[dst])
__global__ __launch_bounds__(256) void seg_z_k(
    const int* __restrict__ ei, const float* __restrict__ ssrc,
    const float* __restrict__ sdst, const float* __restrict__ m, float* __restrict__ z) {
  int e = blockIdx.x * 256 + threadIdx.x;
  if (e >= ETOT) return;
  int src, dst; edge_sd(ei, e, src, dst);
#pragma unroll
  for (int h = 0; h < 4; ++h) {
    float v = leaky(ssrc[src * 4 + h] + sdst[dst * 4 + h]);
    atomicAdd(&z[dst * 4 + h], expf(v - m[dst * 4 + h]));
  }
}

// GAT layer-1 aggregation: agg[dst, h*64+c] += alpha_eh * h[src, h*64+c]. Wave/edge.
__global__ __launch_bounds__(256) void gat_agg1(
    const int* __restrict__ ei, const float* __restrict__ h,
    const float* __restrict__ ssrc, const float* __restrict__ sdst,
    const float* __restrict__ m, const float* __restrict__ z, float* __restrict__ agg) {
  int e = blockIdx.x * 4 + (threadIdx.x >> 6);
  if (e >= ETOT) return;
  int lane = threadIdx.x & 63;
  int src, dst; edge_sd(ei, e, src, dst);
  int hh = lane >> 4;
  float v = leaky(ssrc[src * 4 + hh] + sdst[dst * 4 + hh]);
  float alpha = expf(v - m[dst * 4 + hh]) / z[dst * 4 + hh];
  float4 hv = *(const float4*)(h + (size_t)src * 256 + lane * 4);
  float* o = agg + (size_t)dst * 256 + lane * 4;
  atomicAdd(o + 0, alpha * hv.x);
  atomicAdd(o + 1, alpha * hv.y);
  atomicAdd(o + 2, alpha * hv.z);
  atomicAdd(o + 3, alpha * hv.w);
}

// GAT layer-2 aggregation with head-mean folded in: agg[dst,c] += 0.25*sum_h alpha_h*h2[src,h*64+c]
__global__ __launch_bounds__(256) void gat_agg2(
    const int* __restrict__ ei, const float* __restrict__ h2,
    const float* __restrict__ ssrc, const float* __restrict__ sdst,
    const float* __restrict__ m, const float* __restrict__ z, float* __restrict__ agg) {
  int e = blockIdx.x * 4 + (threadIdx.x >> 6);
  if (e >= ETOT) return;
  int lane = threadIdx.x & 63;
  int src, dst; edge_sd(ei, e, src, dst);
  float acc = 0.f;
#pragma unroll
  for (int h = 0; h < 4; ++h) {
    float v = leaky(ssrc[src * 4 + h] + sdst[dst * 4 + h]);
    float alpha = expf(v - m[dst * 4 + h]) / z[dst * 4 + h];
    acc += alpha * h2[(size_t)src * 256 + h * 64 + lane];
  }
  atomicAdd(&agg[(size_t)dst * 64 + lane], 0.25f * acc);
}

// GCN aggregation: agg[dst,c] += dinv[src]*dinv[dst]*g[src,c]. Wave/edge, 64 cols.
__global__ __launch_bounds__(256) void gcn_agg(
    const int* __restrict__ ei, const float* __restrict__ g,
    const float* __restrict__ dinv, float* __restrict__ agg) {
  int e = blockIdx.x * 4 + (threadIdx.x >> 6);
  if (e >= ETOT) return;
  int lane = threadIdx.x & 63;
  int src, dst; edge_sd(ei, e, src, dst);
  float nrm = dinv[src] * dinv[dst];
  atomicAdd(&agg[(size_t)dst * 64 + lane], nrm * g[(size_t)src * 64 + lane]);
}

// BatchNorm stats: per-feature partial sums (256 features = 256 threads), 64 rows/block
__global__ __launch_bounds__(256) void bn_stats(
    const float* __restrict__ x, float* __restrict__ sum, float* __restrict__ sumsq) {
  int f = threadIdx.x;
  int r0 = blockIdx.x * 64;
  int rend = min(r0 + 64, N_NODES);
  float s = 0.f, s2 = 0.f;
  for (int r = r0; r < rend; ++r) {
    float v = x[(size_t)r * 256 + f];
    s += v; s2 += v * v;
  }
  atomicAdd(&sum[f], s);
  atomicAdd(&sumsq[f], s2);
}

// Apply BN (b1 cancels through BN) + ELU, in place
__global__ __launch_bounds__(256) void bn_apply(
    float* __restrict__ x, const float* __restrict__ sum, const float* __restrict__ sumsq,
    const float* __restrict__ gamma, const float* __restrict__ beta) {
  size_t i = (size_t)blockIdx.x * 256 + threadIdx.x;
  if (i >= (size_t)N_NODES * 256) return;
  int f = (int)(i & 255);
  const float invN = 1.0f / N_NODES;
  float mu = sum[f] * invN;
  float var = sumsq[f] * invN - mu * mu;
  float v = (x[i] - mu) * rsqrtf(var + EPS) * gamma[f] + beta[f];
  x[i] = v > 0.f ? v : expf(v) - 1.0f;
}

__global__ __launch_bounds__(256) void bias_relu_k(float* __restrict__ x, const float* __restrict__ b) {
  int i = blockIdx.x * 256 + threadIdx.x;
  if (i < N_NODES * 64) {
    float v = x[i] + b[i & 63];
    x[i] = fmaxf(v, 0.f);
  }
}

__global__ __launch_bounds__(256) void fuse_k(
    const float* __restrict__ hgat, const float* __restrict__ b2,
    const float* __restrict__ hgcn, const float* __restrict__ bg2,
    const float* __restrict__ dw, float* __restrict__ out) {
  int i = blockIdx.x * 256 + threadIdx.x;
  if (i >= N_NODES * 64) return;
  float w = dw[0];
  out[i] = w * (hgat[i] + b2[i & 63]) + (1.f - w) * (hgcn[i] + bg2[i & 63]);
}

extern "C" void kernel_launch(void* const* d_in, const int* in_sizes, int n_in,
                              void* d_out, int out_size, void* d_ws, size_t ws_size,
                              hipStream_t stream) {
  const float* x     = (const float*)d_in[0];
  const int*   ei    = (const int*)d_in[1];
  const float* dw    = (const float*)d_in[2];
  const float* W1    = (const float*)d_in[3];
  const float* as1   = (const float*)d_in[4];
  const float* ad1   = (const float*)d_in[5];
  // d_in[6] = b1: provably cancels through BatchNorm (constant per-feature shift)
  const float* gamma = (const float*)d_in[7];
  const float* beta  = (const float*)d_in[8];
  const float* W2    = (const float*)d_in[9];
  const float* as2   = (const float*)d_in[10];
  const float* ad2   = (const float*)d_in[11];
  const float* b2    = (const float*)d_in[12];
  const float* Wg1   = (const float*)d_in[13];
  const float* bg1   = (const float*)d_in[14];
  const float* Wg2   = (const float*)d_in[15];
  const float* bg2   = (const float*)d_in[16];
  float* out = (float*)d_out;

  char* p = (char*)d_ws;
  size_t off = 0;
  auto alloc = [&](size_t bytes) {
    char* r = p + off;
    off = (off + bytes + 255) & ~(size_t)255;
    return r;
  };
  float*    bufA  = (float*)alloc((size_t)N_NODES * 256 * 4);  // h1 -> h2 -> g1/g2
  float*    bufB  = (float*)alloc((size_t)N_NODES * 256 * 4);  // agg1/h_bn -> gagg1,gagg2
  float*    bufC  = (float*)alloc((size_t)N_NODES * 64 * 4);   // agg2 = h_gat
  float*    ssrc1 = (float*)alloc((size_t)N_NODES * 4 * 4);
  float*    sdst1 = (float*)alloc((size_t)N_NODES * 4 * 4);
  float*    ssrc2 = (float*)alloc((size_t)N_NODES * 4 * 4);
  float*    sdst2 = (float*)alloc((size_t)N_NODES * 4 * 4);
  unsigned* m1    = (unsigned*)alloc((size_t)N_NODES * 4 * 4);
  float*    z1    = (float*)alloc((size_t)N_NODES * 4 * 4);
  unsigned* m2    = (unsigned*)alloc((size_t)N_NODES * 4 * 4);
  float*    z2    = (float*)alloc((size_t)N_NODES * 4 * 4);
  float*    dinv  = (float*)alloc((size_t)N_NODES * 4);
  float*    bnsum = (float*)alloc(256 * 4);
  float*    bnsq  = (float*)alloc(256 * 4);

  const dim3 blk(256);
  const int egrid  = (ETOT + 255) / 256;    // thread-per-edge kernels
  const int ewgrid = ETOT / 4;              // wave-per-edge kernels (650000 % 4 == 0)

  // zero-init accumulators (graph-capture-safe)
  hipMemsetAsync(bufB, 0, (size_t)N_NODES * 256 * 4, stream);
  hipMemsetAsync(bufC, 0, (size_t)N_NODES * 64 * 4, stream);
  hipMemsetAsync(m1, 0, (size_t)N_NODES * 4 * 4, stream);
  hipMemsetAsync(z1, 0, (size_t)N_NODES * 4 * 4, stream);
  hipMemsetAsync(m2, 0, (size_t)N_NODES * 4 * 4, stream);
  hipMemsetAsync(z2, 0, (size_t)N_NODES * 4 * 4, stream);
  hipMemsetAsync(dinv, 0, (size_t)N_NODES * 4, stream);
  hipMemsetAsync(bnsum, 0, 256 * 4, stream);
  hipMemsetAsync(bnsq, 0, 256 * 4, stream);

  // ---- GAT layer 1 ----
  gemm_f32<<<dim3(782, 4), blk, 0, stream>>>(x, W1, bufA, N_NODES, 256, 128);      // h1
  attn_scores<<<12500, blk, 0, stream>>>(bufA, as1, ad1, ssrc1, sdst1);
  deg_count<<<egrid, blk, 0, stream>>>(ei, dinv);
  dinv_k<<<(N_NODES + 255) / 256, blk, 0, stream>>>(dinv);
  seg_max_k<<<egrid, blk, 0, stream>>>(ei, ssrc1, sdst1, m1);
  decode_k<<<(N_NODES * 4 + 255) / 256, blk, 0, stream>>>(m1, N_NODES * 4);
  seg_z_k<<<egrid, blk, 0, stream>>>(ei, ssrc1, sdst1, (const float*)m1, z1);
  gat_agg1<<<ewgrid, blk, 0, stream>>>(ei, bufA, ssrc1, sdst1, (const float*)m1, z1, bufB);

  // ---- BatchNorm + ELU ----
  bn_stats<<<(N_NODES + 63) / 64, blk, 0, stream>>>(bufB, bnsum, bnsq);
  bn_apply<<<(int)(((size_t)N_NODES * 256 + 255) / 256), blk, 0, stream>>>(bufB, bnsum, bnsq, gamma, beta);

  // ---- GAT layer 2 ----
  gemm_f32<<<dim3(782, 4), blk, 0, stream>>>(bufB, W2, bufA, N_NODES, 256, 256);   // h2
  hipMemsetAsync(bufB, 0, (size_t)N_NODES * 64 * 2 * 4, stream);                   // gagg1+gagg2 (B now dead)
  attn_scores<<<12500, blk, 0, stream>>>(bufA, as2, ad2, ssrc2, sdst2);
  seg_max_k<<<egrid, blk, 0, stream>>>(ei, ssrc2, sdst2, m2);
  decode_k<<<(N_NODES * 4 + 255) / 256, blk, 0, stream>>>(m2, N_NODES * 4);
  seg_z_k<<<egrid, blk, 0, stream>>>(ei, ssrc2, sdst2, (const float*)m2, z2);
  gat_agg2<<<ewgrid, blk, 0, stream>>>(ei, bufA, ssrc2, sdst2, (const float*)m2, z2, bufC);

  // ---- GCN branch ----
  gemm_f32<<<dim3(782, 1), blk, 0, stream>>>(x, Wg1, bufA, N_NODES, 64, 128);      // g1
  gcn_agg<<<ewgrid, blk, 0, stream>>>(ei, bufA, dinv, bufB);                       // gagg1
  bias_relu_k<<<(N_NODES * 64 + 255) / 256, blk, 0, stream>>>(bufB, bg1);          // g
  gemm_f32<<<dim3(782, 1), blk, 0, stream>>>(bufB, Wg2, bufA, N_NODES, 64, 64);    // g2
  gcn_agg<<<ewgrid, blk, 0, stream>>>(ei, bufA, dinv, bufB + (size_t)N_NODES * 64); // gagg2

  // ---- drift-weighted fusion ----
  fuse_k<<<(N_NODES * 64 + 255) / 256, blk, 0, stream>>>(
      bufC, b2, bufB + (size_t)N_NODES * 64, bg2, dw, out);
}

// Round 2
// 780.929 us; speedup vs baseline: 4.5280x; 4.5280x over previous
//
#include <hip/hip_runtime.h>

#define N_NODES 50000
#define N_EDGES 600000
#define ETOT    650000   // N_EDGES + N_NODES self loops
#define EPS     1e-5f
#define SCAN_BLOCKS 196  // ceil(50000/256)

static __device__ __forceinline__ float leaky(float v) { return v >= 0.f ? v : 0.2f * v; }

// ---------------------------------------------------------------------------
// Tiled fp32 GEMM: C[M,N] = A[M,K] @ B[K,N].  64x64 tile, 256 threads, 4x4/thread.
// ---------------------------------------------------------------------------
__global__ __launch_bounds__(256) void gemm_f32(
    const float* __restrict__ A, const float* __restrict__ B, float* __restrict__ C,
    int M, int N, int K) {
  __shared__ float As[32][68];
  __shared__ float Bs[32][64];
  const int tid = threadIdx.x;
  const int tx = tid & 15, ty = tid >> 4;
  const int m0 = blockIdx.x * 64, n0 = blockIdx.y * 64;
  float acc[4][4] = {};
  for (int k0 = 0; k0 < K; k0 += 32) {
#pragma unroll
    for (int i = 0; i < 8; ++i) {
      int idx = tid + i * 256;
      int m = idx >> 5, k = idx & 31;
      int gm = m0 + m;
      As[k][m] = (gm < M) ? A[(size_t)gm * K + k0 + k] : 0.f;
    }
#pragma unroll
    for (int i = 0; i < 8; ++i) {
      int idx = tid + i * 256;
      int k = idx >> 6, n = idx & 63;
      Bs[k][n] = B[(size_t)(k0 + k) * N + n0 + n];
    }
    __syncthreads();
#pragma unroll
    for (int k = 0; k < 32; ++k) {
      float a0 = As[k][ty * 4 + 0], a1 = As[k][ty * 4 + 1];
      float a2 = As[k][ty * 4 + 2], a3 = As[k][ty * 4 + 3];
      float b0 = Bs[k][tx * 4 + 0], b1 = Bs[k][tx * 4 + 1];
      float b2 = Bs[k][tx * 4 + 2], b3 = Bs[k][tx * 4 + 3];
      acc[0][0] += a0 * b0; acc[0][1] += a0 * b1; acc[0][2] += a0 * b2; acc[0][3] += a0 * b3;
      acc[1][0] += a1 * b0; acc[1][1] += a1 * b1; acc[1][2] += a1 * b2; acc[1][3] += a1 * b3;
      acc[2][0] += a2 * b0; acc[2][1] += a2 * b1; acc[2][2] += a2 * b2; acc[2][3] += a2 * b3;
      acc[3][0] += a3 * b0; acc[3][1] += a3 * b1; acc[3][2] += a3 * b2; acc[3][3] += a3 * b3;
    }
    __syncthreads();
  }
#pragma unroll
  for (int i = 0; i < 4; ++i) {
    int gm = m0 + ty * 4 + i;
    if (gm < M) {
#pragma unroll
      for (int j = 0; j < 4; ++j) C[(size_t)gm * N + n0 + tx * 4 + j] = acc[i][j];
    }
  }
}

// ---------------------------------------------------------------------------
// Per-node attention scores (wave per row; 16-lane group = one head)
// ---------------------------------------------------------------------------
__global__ __launch_bounds__(256) void attn_scores(
    const float* __restrict__ h, const float* __restrict__ a_src,
    const float* __restrict__ a_dst, float* __restrict__ ssrc, float* __restrict__ sdst) {
  const int wave = threadIdx.x >> 6, lane = threadIdx.x & 63;
  const int row = blockIdx.x * 4 + wave;
  if (row >= N_NODES) return;
  const float4 hv = *(const float4*)(h + (size_t)row * 256 + lane * 4);
  const float4 as = *(const float4*)(a_src + lane * 4);
  const float4 ad = *(const float4*)(a_dst + lane * 4);
  float ps = hv.x * as.x + hv.y * as.y + hv.z * as.z + hv.w * as.w;
  float pd = hv.x * ad.x + hv.y * ad.y + hv.z * ad.z + hv.w * ad.w;
#pragma unroll
  for (int off = 1; off < 16; off <<= 1) {
    ps += __shfl_xor(ps, off);
    pd += __shfl_xor(pd, off);
  }
  if ((lane & 15) == 0) {
    int hh = lane >> 4;
    ssrc[row * 4 + hh] = ps;
    sdst[row * 4 + hh] = pd;
  }
}

// ---------------------------------------------------------------------------
// CSR build: degree count -> exclusive scan -> scatter src by dst
// ---------------------------------------------------------------------------
static __device__ __forceinline__ void edge_sd(const int* ei, int e, int& src, int& dst) {
  if (e < N_EDGES) { src = ei[e]; dst = ei[N_EDGES + e]; }
  else             { src = dst = e - N_EDGES; }
}

__global__ __launch_bounds__(256) void deg_count_int(const int* __restrict__ ei, int* __restrict__ degi) {
  int e = blockIdx.x * 256 + threadIdx.x;
  if (e >= ETOT) return;
  int dst = (e < N_EDGES) ? ei[N_EDGES + e] : (e - N_EDGES);
  atomicAdd(&degi[dst], 1);
}

__global__ __launch_bounds__(256) void scan1(const int* __restrict__ degi,
                                             int* __restrict__ partial, int* __restrict__ bsum) {
  __shared__ int sm[256];
  int i = blockIdx.x * 256 + threadIdx.x;
  int v = (i < N_NODES) ? degi[i] : 0;
  sm[threadIdx.x] = v;
  __syncthreads();
#pragma unroll
  for (int off = 1; off < 256; off <<= 1) {
    int t = (threadIdx.x >= off) ? sm[threadIdx.x - off] : 0;
    __syncthreads();
    sm[threadIdx.x] += t;
    __syncthreads();
  }
  if (i < N_NODES) partial[i] = sm[threadIdx.x] - v;   // exclusive
  if (threadIdx.x == 255) bsum[blockIdx.x] = sm[255];
}

__global__ __launch_bounds__(256) void scan2(int* __restrict__ bsum) {
  __shared__ int sm[256];
  int v = (threadIdx.x < SCAN_BLOCKS) ? bsum[threadIdx.x] : 0;
  sm[threadIdx.x] = v;
  __syncthreads();
#pragma unroll
  for (int off = 1; off < 256; off <<= 1) {
    int t = (threadIdx.x >= off) ? sm[threadIdx.x - off] : 0;
    __syncthreads();
    sm[threadIdx.x] += t;
    __syncthreads();
  }
  if (threadIdx.x < SCAN_BLOCKS) bsum[threadIdx.x] = sm[threadIdx.x] - v;  // exclusive
}

__global__ __launch_bounds__(256) void scan3(int* __restrict__ rowstart, const int* __restrict__ bsum,
                                             int* __restrict__ cursor, const int* __restrict__ degi,
                                             float* __restrict__ dinv) {
  int i = blockIdx.x * 256 + threadIdx.x;
  if (i >= N_NODES) return;
  int r = rowstart[i] + bsum[blockIdx.x];
  rowstart[i] = r;
  cursor[i] = r;
  dinv[i] = rsqrtf(fmaxf((float)degi[i], 1.0f));
}

__global__ __launch_bounds__(256) void scatter_k(const int* __restrict__ ei,
                                                 int* __restrict__ cursor, int* __restrict__ csr) {
  int e = blockIdx.x * 256 + threadIdx.x;
  if (e >= ETOT) return;
  int src, dst; edge_sd(ei, e, src, dst);
  int pos = atomicAdd(&cursor[dst], 1);
  csr[pos] = src;
}

// ---------------------------------------------------------------------------
// GAT layer-1 aggregation (gather, online softmax w/o max-shift; logits bounded).
// Wave per dst; lane covers 256 cols as float4; 16-lane group = one head.
// ---------------------------------------------------------------------------
__global__ __launch_bounds__(256) void gat_agg1_csr(
    const int* __restrict__ rowstart, const int* __restrict__ degi, const int* __restrict__ csr,
    const float* __restrict__ h, const float* __restrict__ ssrc, const float* __restrict__ sdst,
    float* __restrict__ outp) {
  int dst = blockIdx.x * 4 + (threadIdx.x >> 6);
  if (dst >= N_NODES) return;
  int lane = threadIdx.x & 63;
  int hh = lane >> 4;
  int rs = rowstart[dst], re = rs + degi[dst];
  float sd = sdst[dst * 4 + hh];
  float z = 0.f;
  float ax = 0.f, ay = 0.f, az = 0.f, aw = 0.f;
  for (int j = rs; j < re; ++j) {
    int src = csr[j];
    float p = __expf(leaky(ssrc[src * 4 + hh] + sd));
    z += p;
    const float4 hv = *(const float4*)(h + (size_t)src * 256 + lane * 4);
    ax += p * hv.x; ay += p * hv.y; az += p * hv.z; aw += p * hv.w;
  }
  float inv = 1.f / z;
  float4 o = { ax * inv, ay * inv, az * inv, aw * inv };
  *(float4*)(outp + (size_t)dst * 256 + lane * 4) = o;
}

// GAT layer-2 aggregation with head-mean; wave per dst; lane covers 64 cols.
__global__ __launch_bounds__(256) void gat_agg2_csr(
    const int* __restrict__ rowstart, const int* __restrict__ degi, const int* __restrict__ csr,
    const float* __restrict__ h2, const float* __restrict__ ssrc, const float* __restrict__ sdst,
    float* __restrict__ outp) {
  int dst = blockIdx.x * 4 + (threadIdx.x >> 6);
  if (dst >= N_NODES) return;
  int lane = threadIdx.x & 63;
  int rs = rowstart[dst], re = rs + degi[dst];
  const float4 sd = *(const float4*)(sdst + dst * 4);
  float z0 = 0.f, z1 = 0.f, z2 = 0.f, z3 = 0.f;
  float a0 = 0.f, a1 = 0.f, a2 = 0.f, a3 = 0.f;
  for (int j = rs; j < re; ++j) {
    int src = csr[j];
    const float4 ss = *(const float4*)(ssrc + src * 4);
    float p0 = __expf(leaky(ss.x + sd.x));
    float p1 = __expf(leaky(ss.y + sd.y));
    float p2 = __expf(leaky(ss.z + sd.z));
    float p3 = __expf(leaky(ss.w + sd.w));
    z0 += p0; z1 += p1; z2 += p2; z3 += p3;
    const float* hb = h2 + (size_t)src * 256;
    a0 += p0 * hb[lane];
    a1 += p1 * hb[64 + lane];
    a2 += p2 * hb[128 + lane];
    a3 += p3 * hb[192 + lane];
  }
  outp[(size_t)dst * 64 + lane] = 0.25f * (a0 / z0 + a1 / z1 + a2 / z2 + a3 / z3);
}

// GCN layer-1 aggregation + bias + ReLU (gather). Wave per dst, 64 cols.
__global__ __launch_bounds__(256) void gcn_agg_relu(
    const int* __restrict__ rowstart, const int* __restrict__ degi, const int* __restrict__ csr,
    const float* __restrict__ g, const float* __restrict__ dinv, const float* __restrict__ bias,
    float* __restrict__ outp) {
  int dst = blockIdx.x * 4 + (threadIdx.x >> 6);
  if (dst >= N_NODES) return;
  int lane = threadIdx.x & 63;
  int rs = rowstart[dst], re = rs + degi[dst];
  float acc = 0.f;
  for (int j = rs; j < re; ++j) {
    int src = csr[j];
    acc += dinv[src] * g[(size_t)src * 64 + lane];
  }
  float v = acc * dinv[dst] + bias[lane];
  outp[(size_t)dst * 64 + lane] = fmaxf(v, 0.f);
}

// GCN layer-2 aggregation + bias, fused with drift-weighted combine. Wave per dst.
__global__ __launch_bounds__(256) void gcn_agg_fuse(
    const int* __restrict__ rowstart, const int* __restrict__ degi, const int* __restrict__ csr,
    const float* __restrict__ g2, const float* __restrict__ dinv, const float* __restrict__ bg2,
    const float* __restrict__ hgat, const float* __restrict__ b2, const float* __restrict__ dw,
    float* __restrict__ outp) {
  int dst = blockIdx.x * 4 + (threadIdx.x >> 6);
  if (dst >= N_NODES) return;
  int lane = threadIdx.x & 63;
  int rs = rowstart[dst], re = rs + degi[dst];
  float acc = 0.f;
  for (int j = rs; j < re; ++j) {
    int src = csr[j];
    acc += dinv[src] * g2[(size_t)src * 64 + lane];
  }
  float w = dw[0];
  float gcn = acc * dinv[dst] + bg2[lane];
  float gat = hgat[(size_t)dst * 64 + lane] + b2[lane];
  outp[(size_t)dst * 64 + lane] = w * gat + (1.f - w) * gcn;
}

// ---------------------------------------------------------------------------
// BatchNorm
// ---------------------------------------------------------------------------
__global__ __launch_bounds__(256) void bn_stats(
    const float* __restrict__ x, float* __restrict__ sum, float* __restrict__ sumsq) {
  int f = threadIdx.x;
  int r0 = blockIdx.x * 64;
  int rend = min(r0 + 64, N_NODES);
  float s = 0.f, s2 = 0.f;
  for (int r = r0; r < rend; ++r) {
    float v = x[(size_t)r * 256 + f];
    s += v; s2 += v * v;
  }
  atomicAdd(&sum[f], s);
  atomicAdd(&sumsq[f], s2);
}

__global__ __launch_bounds__(256) void bn_apply(
    float* __restrict__ x, const float* __restrict__ sum, const float* __restrict__ sumsq,
    const float* __restrict__ gamma, const float* __restrict__ beta) {
  size_t i = (size_t)blockIdx.x * 256 + threadIdx.x;
  if (i >= (size_t)N_NODES * 256) return;
  int f = (int)(i & 255);
  const float invN = 1.0f / N_NODES;
  float mu = sum[f] * invN;
  float var = sumsq[f] * invN - mu * mu;
  float v = (x[i] - mu) * rsqrtf(var + EPS) * gamma[f] + beta[f];
  x[i] = v > 0.f ? v : expf(v) - 1.0f;
}

extern "C" void kernel_launch(void* const* d_in, const int* in_sizes, int n_in,
                              void* d_out, int out_size, void* d_ws, size_t ws_size,
                              hipStream_t stream) {
  const float* x     = (const float*)d_in[0];
  const int*   ei    = (const int*)d_in[1];
  const float* dw    = (const float*)d_in[2];
  const float* W1    = (const float*)d_in[3];
  const float* as1   = (const float*)d_in[4];
  const float* ad1   = (const float*)d_in[5];
  // d_in[6] = b1: cancels through BatchNorm (constant per-feature shift)
  const float* gamma = (const float*)d_in[7];
  const float* beta  = (const float*)d_in[8];
  const float* W2    = (const float*)d_in[9];
  const float* as2   = (const float*)d_in[10];
  const float* ad2   = (const float*)d_in[11];
  const float* b2    = (const float*)d_in[12];
  const float* Wg1   = (const float*)d_in[13];
  const float* bg1   = (const float*)d_in[14];
  const float* Wg2   = (const float*)d_in[15];
  const float* bg2   = (const float*)d_in[16];
  float* out = (float*)d_out;

  char* p = (char*)d_ws;
  size_t off = 0;
  auto alloc = [&](size_t bytes) {
    char* r = p + off;
    off = (off + bytes + 255) & ~(size_t)255;
    return r;
  };
  float* bufA  = (float*)alloc((size_t)N_NODES * 256 * 4);  // h1 -> h2
  float* bufB  = (float*)alloc((size_t)N_NODES * 256 * 4);  // agg1/h_bn -> g1,g,g2 (4x N*64 slots)
  float* bufC  = (float*)alloc((size_t)N_NODES * 64 * 4);   // h_gat
  float* ssrc1 = (float*)alloc((size_t)N_NODES * 4 * 4);
  float* sdst1 = (float*)alloc((size_t)N_NODES * 4 * 4);
  float* ssrc2 = (float*)alloc((size_t)N_NODES * 4 * 4);
  float* sdst2 = (float*)alloc((size_t)N_NODES * 4 * 4);
  int*   degi  = (int*)alloc((size_t)N_NODES * 4);
  int*   rowst = (int*)alloc((size_t)N_NODES * 4);
  int*   cursor= (int*)alloc((size_t)N_NODES * 4);
  int*   bsum  = (int*)alloc(SCAN_BLOCKS * 4);
  float* dinv  = (float*)alloc((size_t)N_NODES * 4);
  int*   csr   = (int*)alloc((size_t)ETOT * 4);
  float* bnsum = (float*)alloc(256 * 4);
  float* bnsq  = (float*)alloc(256 * 4);

  const dim3 blk(256);
  const int egrid = (ETOT + 255) / 256;
  const int ngrid = 12500;   // wave-per-node kernels: 12500*4 = 50000

  hipMemsetAsync(degi, 0, (size_t)N_NODES * 4, stream);
  hipMemsetAsync(bnsum, 0, 256 * 4, stream);
  hipMemsetAsync(bnsq, 0, 256 * 4, stream);

  // ---- CSR build (shared by both branches) ----
  deg_count_int<<<egrid, blk, 0, stream>>>(ei, degi);
  scan1<<<SCAN_BLOCKS, blk, 0, stream>>>(degi, rowst, bsum);
  scan2<<<1, blk, 0, stream>>>(bsum);
  scan3<<<SCAN_BLOCKS, blk, 0, stream>>>(rowst, bsum, cursor, degi, dinv);
  scatter_k<<<egrid, blk, 0, stream>>>(ei, cursor, csr);

  // ---- GAT layer 1 ----
  gemm_f32<<<dim3(782, 4), blk, 0, stream>>>(x, W1, bufA, N_NODES, 256, 128);     // h1
  attn_scores<<<ngrid, blk, 0, stream>>>(bufA, as1, ad1, ssrc1, sdst1);
  gat_agg1_csr<<<ngrid, blk, 0, stream>>>(rowst, degi, csr, bufA, ssrc1, sdst1, bufB);

  // ---- BatchNorm + ELU ----
  bn_stats<<<(N_NODES + 63) / 64, blk, 0, stream>>>(bufB, bnsum, bnsq);
  bn_apply<<<(int)(((size_t)N_NODES * 256 + 255) / 256), blk, 0, stream>>>(bufB, bnsum, bnsq, gamma, beta);

  // ---- GAT layer 2 ----
  gemm_f32<<<dim3(782, 4), blk, 0, stream>>>(bufB, W2, bufA, N_NODES, 256, 256);  // h2
  attn_scores<<<ngrid, blk, 0, stream>>>(bufA, as2, ad2, ssrc2, sdst2);
  gat_agg2_csr<<<ngrid, blk, 0, stream>>>(rowst, degi, csr, bufA, ssrc2, sdst2, bufC);

  // ---- GCN branch (bufB slots: 0=g1, 1=g, 2=g2) ----
  float* g1 = bufB;
  float* g  = bufB + (size_t)N_NODES * 64;
  float* g2 = bufB + (size_t)N_NODES * 128;
  gemm_f32<<<dim3(782, 1), blk, 0, stream>>>(x, Wg1, g1, N_NODES, 64, 128);
  gcn_agg_relu<<<ngrid, blk, 0, stream>>>(rowst, degi, csr, g1, dinv, bg1, g);
  gemm_f32<<<dim3(782, 1), blk, 0, stream>>>(g, Wg2, g2, N_NODES, 64, 64);
  gcn_agg_fuse<<<ngrid, blk, 0, stream>>>(rowst, degi, csr, g2, dinv, bg2, bufC, b2, dw, out);
}

// Round 3
// 668.249 us; speedup vs baseline: 5.2916x; 1.1686x over previous
//
#include <hip/hip_runtime.h>

#define N_NODES 50000
#define M_PAD   50048    // 782 * 64, zero-padded rows for MFMA tile staging
#define N_EDGES 600000
#define ETOT    650000   // N_EDGES + N_NODES self loops
#define EPS     1e-5f
#define SCAN_BLOCKS 196  // ceil(50000/256)

typedef short bf16x8 __attribute__((ext_vector_type(8)));
typedef float f32x4  __attribute__((ext_vector_type(4)));

static __device__ __forceinline__ float leaky(float v) { return v >= 0.f ? v : 0.2f * v; }

// round-to-nearest-even float -> bf16 bits
static __device__ __forceinline__ ushort f2bf(float f) {
  unsigned u = __float_as_uint(f);
  return (ushort)((u + 0x7fff + ((u >> 16) & 1)) >> 16);
}

// ---------------------------------------------------------------------------
// bf16 MFMA GEMM: C[M,Nfull] = A[M_PAD,K]bf16 @ Bt[Nfull,K]bf16^T, fp32 out.
// 64x64 tile, BK=64, 4 waves each computing a 32x32 quadrant via 16x16x32 MFMA.
// LDS XOR-swizzle (byte ^= (row&7)<<4) keeps fragment ds_read_b128 2-way max.
// ---------------------------------------------------------------------------
template <int K>
__global__ __launch_bounds__(256) void gemm_bf16(
    const ushort* __restrict__ A, const ushort* __restrict__ Bt,
    float* __restrict__ C, int M, int Nfull) {
  __shared__ char As[64 * 128];   // 64 rows x 64 bf16 (128B)
  __shared__ char Bs[64 * 128];
  const int tid = threadIdx.x;
  const int w = tid >> 6, lane = tid & 63;
  const int wr = w >> 1, wc = w & 1;
  const int m0 = blockIdx.x * 64, n0 = blockIdx.y * 64;

  f32x4 acc[2][2] = {};

  for (int k0 = 0; k0 < K; k0 += 64) {
    __syncthreads();
#pragma unroll
    for (int j = 0; j < 2; ++j) {
      int i = tid + j * 256;               // 0..511 chunk id (16B chunks)
      int row = i >> 3;
      int cb = (i & 7) * 16;               // byte within 128B row
      int dst = row * 128 + (cb ^ ((row & 7) << 4));
      uint4 va = *(const uint4*)((const char*)A + ((size_t)(m0 + row) * K + k0) * 2 + cb);
      *(uint4*)(As + dst) = va;
      uint4 vb = *(const uint4*)((const char*)Bt + ((size_t)(n0 + row) * K + k0) * 2 + cb);
      *(uint4*)(Bs + dst) = vb;
    }
    __syncthreads();
#pragma unroll
    for (int c = 0; c < 2; ++c) {
      bf16x8 af[2], bfr[2];
      int kb = (lane >> 4) * 16 + c * 64;
#pragma unroll
      for (int m = 0; m < 2; ++m) {
        int lr = wr * 32 + m * 16 + (lane & 15);
        af[m] = *(const bf16x8*)(As + lr * 128 + (kb ^ ((lr & 7) << 4)));
      }
#pragma unroll
      for (int n = 0; n < 2; ++n) {
        int lr = wc * 32 + n * 16 + (lane & 15);
        bfr[n] = *(const bf16x8*)(Bs + lr * 128 + (kb ^ ((lr & 7) << 4)));
      }
#pragma unroll
      for (int m = 0; m < 2; ++m)
#pragma unroll
        for (int n = 0; n < 2; ++n)
          acc[m][n] = __builtin_amdgcn_mfma_f32_16x16x32_bf16(af[m], bfr[n], acc[m][n], 0, 0, 0);
    }
  }
#pragma unroll
  for (int m = 0; m < 2; ++m)
#pragma unroll
    for (int n = 0; n < 2; ++n)
#pragma unroll
      for (int i = 0; i < 4; ++i) {
        int row = m0 + wr * 32 + m * 16 + (lane >> 4) * 4 + i;
        int col = n0 + wc * 32 + n * 16 + (lane & 15);
        if (row < M) C[(size_t)row * Nfull + col] = acc[m][n][i];
      }
}

// cast x (fp32 [N_NODES,128]) -> bf16 [M_PAD,128], pad rows zeroed. 4 elems/thread.
__global__ __launch_bounds__(256) void cast_x_bf16(const float* __restrict__ x, ushort* __restrict__ o) {
  int i = blockIdx.x * 256 + threadIdx.x;          // chunk of 4
  if (i >= M_PAD * 32) return;
  int i4 = i * 4;
  int row = i4 >> 7;
  ushort4 r;
  if (row < N_NODES) {
    const float4 v = *(const float4*)(x + i4);
    r.x = f2bf(v.x); r.y = f2bf(v.y); r.z = f2bf(v.z); r.w = f2bf(v.w);
  } else {
    r.x = r.y = r.z = r.w = 0;
  }
  *(ushort4*)(o + i4) = r;
}

// transpose-cast weights: W[K,N] fp32 -> Wt[N,K] bf16
__global__ __launch_bounds__(256) void tcast_w(const float* __restrict__ W, ushort* __restrict__ Wt,
                                               int K, int N) {
  int i = blockIdx.x * 256 + threadIdx.x;
  if (i >= K * N) return;
  int k = i / N, n = i - k * N;
  Wt[n * K + k] = f2bf(W[i]);
}

// ---------------------------------------------------------------------------
// fp32 GEMM (kept for the small GCN layers)
// ---------------------------------------------------------------------------
__global__ __launch_bounds__(256) void gemm_f32(
    const float* __restrict__ A, const float* __restrict__ B, float* __restrict__ C,
    int M, int N, int K) {
  __shared__ float As[32][68];
  __shared__ float Bs[32][64];
  const int tid = threadIdx.x;
  const int tx = tid & 15, ty = tid >> 4;
  const int m0 = blockIdx.x * 64, n0 = blockIdx.y * 64;
  float acc[4][4] = {};
  for (int k0 = 0; k0 < K; k0 += 32) {
#pragma unroll
    for (int i = 0; i < 8; ++i) {
      int idx = tid + i * 256;
      int m = idx >> 5, k = idx & 31;
      int gm = m0 + m;
      As[k][m] = (gm < M) ? A[(size_t)gm * K + k0 + k] : 0.f;
    }
#pragma unroll
    for (int i = 0; i < 8; ++i) {
      int idx = tid + i * 256;
      int k = idx >> 6, n = idx & 63;
      Bs[k][n] = B[(size_t)(k0 + k) * N + n0 + n];
    }
    __syncthreads();
#pragma unroll
    for (int k = 0; k < 32; ++k) {
      float a0 = As[k][ty * 4 + 0], a1 = As[k][ty * 4 + 1];
      float a2 = As[k][ty * 4 + 2], a3 = As[k][ty * 4 + 3];
      float b0 = Bs[k][tx * 4 + 0], b1 = Bs[k][tx * 4 + 1];
      float b2 = Bs[k][tx * 4 + 2], b3 = Bs[k][tx * 4 + 3];
      acc[0][0] += a0 * b0; acc[0][1] += a0 * b1; acc[0][2] += a0 * b2; acc[0][3] += a0 * b3;
      acc[1][0] += a1 * b0; acc[1][1] += a1 * b1; acc[1][2] += a1 * b2; acc[1][3] += a1 * b3;
      acc[2][0] += a2 * b0; acc[2][1] += a2 * b1; acc[2][2] += a2 * b2; acc[2][3] += a2 * b3;
      acc[3][0] += a3 * b0; acc[3][1] += a3 * b1; acc[3][2] += a3 * b2; acc[3][3] += a3 * b3;
    }
    __syncthreads();
  }
#pragma unroll
  for (int i = 0; i < 4; ++i) {
    int gm = m0 + ty * 4 + i;
    if (gm < M) {
#pragma unroll
      for (int j = 0; j < 4; ++j) C[(size_t)gm * N + n0 + tx * 4 + j] = acc[i][j];
    }
  }
}

// ---------------------------------------------------------------------------
// Per-node attention scores (wave per row; 16-lane group = one head)
// ---------------------------------------------------------------------------
__global__ __launch_bounds__(256) void attn_scores(
    const float* __restrict__ h, const float* __restrict__ a_src,
    const float* __restrict__ a_dst, float* __restrict__ ssrc, float* __restrict__ sdst) {
  const int wave = threadIdx.x >> 6, lane = threadIdx.x & 63;
  const int row = blockIdx.x * 4 + wave;
  if (row >= N_NODES) return;
  const float4 hv = *(const float4*)(h + (size_t)row * 256 + lane * 4);
  const float4 as = *(const float4*)(a_src + lane * 4);
  const float4 ad = *(const float4*)(a_dst + lane * 4);
  float ps = hv.x * as.x + hv.y * as.y + hv.z * as.z + hv.w * as.w;
  float pd = hv.x * ad.x + hv.y * ad.y + hv.z * ad.z + hv.w * ad.w;
#pragma unroll
  for (int off = 1; off < 16; off <<= 1) {
    ps += __shfl_xor(ps, off);
    pd += __shfl_xor(pd, off);
  }
  if ((lane & 15) == 0) {
    int hh = lane >> 4;
    ssrc[row * 4 + hh] = ps;
    sdst[row * 4 + hh] = pd;
  }
}

// ---------------------------------------------------------------------------
// CSR build
// ---------------------------------------------------------------------------
static __device__ __forceinline__ void edge_sd(const int* ei, int e, int& src, int& dst) {
  if (e < N_EDGES) { src = ei[e]; dst = ei[N_EDGES + e]; }
  else             { src = dst = e - N_EDGES; }
}

__global__ __launch_bounds__(256) void deg_count_int(const int* __restrict__ ei, int* __restrict__ degi) {
  int e = blockIdx.x * 256 + threadIdx.x;
  if (e >= ETOT) return;
  int dst = (e < N_EDGES) ? ei[N_EDGES + e] : (e - N_EDGES);
  atomicAdd(&degi[dst], 1);
}

__global__ __launch_bounds__(256) void scan1(const int* __restrict__ degi,
                                             int* __restrict__ partial, int* __restrict__ bsum) {
  __shared__ int sm[256];
  int i = blockIdx.x * 256 + threadIdx.x;
  int v = (i < N_NODES) ? degi[i] : 0;
  sm[threadIdx.x] = v;
  __syncthreads();
#pragma unroll
  for (int off = 1; off < 256; off <<= 1) {
    int t = (threadIdx.x >= off) ? sm[threadIdx.x - off] : 0;
    __syncthreads();
    sm[threadIdx.x] += t;
    __syncthreads();
  }
  if (i < N_NODES) partial[i] = sm[threadIdx.x] - v;
  if (threadIdx.x == 255) bsum[blockIdx.x] = sm[255];
}

__global__ __launch_bounds__(256) void scan2(int* __restrict__ bsum) {
  __shared__ int sm[256];
  int v = (threadIdx.x < SCAN_BLOCKS) ? bsum[threadIdx.x] : 0;
  sm[threadIdx.x] = v;
  __syncthreads();
#pragma unroll
  for (int off = 1; off < 256; off <<= 1) {
    int t = (threadIdx.x >= off) ? sm[threadIdx.x - off] : 0;
    __syncthreads();
    sm[threadIdx.x] += t;
    __syncthreads();
  }
  if (threadIdx.x < SCAN_BLOCKS) bsum[threadIdx.x] = sm[threadIdx.x] - v;
}

__global__ __launch_bounds__(256) void scan3(int* __restrict__ rowstart, const int* __restrict__ bsum,
                                             int* __restrict__ cursor, const int* __restrict__ degi,
                                             float* __restrict__ dinv) {
  int i = blockIdx.x * 256 + threadIdx.x;
  if (i >= N_NODES) return;
  int r = rowstart[i] + bsum[blockIdx.x];
  rowstart[i] = r;
  cursor[i] = r;
  dinv[i] = rsqrtf(fmaxf((float)degi[i], 1.0f));
}

__global__ __launch_bounds__(256) void scatter_k(const int* __restrict__ ei,
                                                 int* __restrict__ cursor, int* __restrict__ csr) {
  int e = blockIdx.x * 256 + threadIdx.x;
  if (e >= ETOT) return;
  int src, dst; edge_sd(ei, e, src, dst);
  int pos = atomicAdd(&cursor[dst], 1);
  csr[pos] = src;
}

// ---------------------------------------------------------------------------
// GAT aggregations (gather over CSR, online softmax; logits bounded)
// ---------------------------------------------------------------------------
__global__ __launch_bounds__(256) void gat_agg1_csr(
    const int* __restrict__ rowstart, const int* __restrict__ degi, const int* __restrict__ csr,
    const float* __restrict__ h, const float* __restrict__ ssrc, const float* __restrict__ sdst,
    float* __restrict__ outp) {
  int dst = blockIdx.x * 4 + (threadIdx.x >> 6);
  if (dst >= N_NODES) return;
  int lane = threadIdx.x & 63;
  int hh = lane >> 4;
  int rs = rowstart[dst], re = rs + degi[dst];
  float sd = sdst[dst * 4 + hh];
  float z = 0.f;
  float ax = 0.f, ay = 0.f, az = 0.f, aw = 0.f;
  for (int j = rs; j < re; ++j) {
    int src = csr[j];
    float p = __expf(leaky(ssrc[src * 4 + hh] + sd));
    z += p;
    const float4 hv = *(const float4*)(h + (size_t)src * 256 + lane * 4);
    ax += p * hv.x; ay += p * hv.y; az += p * hv.z; aw += p * hv.w;
  }
  float inv = 1.f / z;
  float4 o = { ax * inv, ay * inv, az * inv, aw * inv };
  *(float4*)(outp + (size_t)dst * 256 + lane * 4) = o;
}

__global__ __launch_bounds__(256) void gat_agg2_csr(
    const int* __restrict__ rowstart, const int* __restrict__ degi, const int* __restrict__ csr,
    const float* __restrict__ h2, const float* __restrict__ ssrc, const float* __restrict__ sdst,
    float* __restrict__ outp) {
  int dst = blockIdx.x * 4 + (threadIdx.x >> 6);
  if (dst >= N_NODES) return;
  int lane = threadIdx.x & 63;
  int rs = rowstart[dst], re = rs + degi[dst];
  const float4 sd = *(const float4*)(sdst + dst * 4);
  float z0 = 0.f, z1 = 0.f, z2 = 0.f, z3 = 0.f;
  float a0 = 0.f, a1 = 0.f, a2 = 0.f, a3 = 0.f;
  for (int j = rs; j < re; ++j) {
    int src = csr[j];
    const float4 ss = *(const float4*)(ssrc + src * 4);
    float p0 = __expf(leaky(ss.x + sd.x));
    float p1 = __expf(leaky(ss.y + sd.y));
    float p2 = __expf(leaky(ss.z + sd.z));
    float p3 = __expf(leaky(ss.w + sd.w));
    z0 += p0; z1 += p1; z2 += p2; z3 += p3;
    const float* hb = h2 + (size_t)src * 256;
    a0 += p0 * hb[lane];
    a1 += p1 * hb[64 + lane];
    a2 += p2 * hb[128 + lane];
    a3 += p3 * hb[192 + lane];
  }
  outp[(size_t)dst * 64 + lane] = 0.25f * (a0 / z0 + a1 / z1 + a2 / z2 + a3 / z3);
}

__global__ __launch_bounds__(256) void gcn_agg_relu(
    const int* __restrict__ rowstart, const int* __restrict__ degi, const int* __restrict__ csr,
    const float* __restrict__ g, const float* __restrict__ dinv, const float* __restrict__ bias,
    float* __restrict__ outp) {
  int dst = blockIdx.x * 4 + (threadIdx.x >> 6);
  if (dst >= N_NODES) return;
  int lane = threadIdx.x & 63;
  int rs = rowstart[dst], re = rs + degi[dst];
  float acc = 0.f;
  for (int j = rs; j < re; ++j) {
    int src = csr[j];
    acc += dinv[src] * g[(size_t)src * 64 + lane];
  }
  float v = acc * dinv[dst] + bias[lane];
  outp[(size_t)dst * 64 + lane] = fmaxf(v, 0.f);
}

__global__ __launch_bounds__(256) void gcn_agg_fuse(
    const int* __restrict__ rowstart, const int* __restrict__ degi, const int* __restrict__ csr,
    const float* __restrict__ g2, const float* __restrict__ dinv, const float* __restrict__ bg2,
    const float* __restrict__ hgat, const float* __restrict__ b2, const float* __restrict__ dw,
    float* __restrict__ outp) {
  int dst = blockIdx.x * 4 + (threadIdx.x >> 6);
  if (dst >= N_NODES) return;
  int lane = threadIdx.x & 63;
  int rs = rowstart[dst], re = rs + degi[dst];
  float acc = 0.f;
  for (int j = rs; j < re; ++j) {
    int src = csr[j];
    acc += dinv[src] * g2[(size_t)src * 64 + lane];
  }
  float w = dw[0];
  float gcn = acc * dinv[dst] + bg2[lane];
  float gat = hgat[(size_t)dst * 64 + lane] + b2[lane];
  outp[(size_t)dst * 64 + lane] = w * gat + (1.f - w) * gcn;
}

// ---------------------------------------------------------------------------
// BatchNorm
// ---------------------------------------------------------------------------
__global__ __launch_bounds__(256) void bn_stats(
    const float* __restrict__ x, float* __restrict__ sum, float* __restrict__ sumsq) {
  int f = threadIdx.x;
  int r0 = blockIdx.x * 64;
  int rend = min(r0 + 64, N_NODES);
  float s = 0.f, s2 = 0.f;
  for (int r = r0; r < rend; ++r) {
    float v = x[(size_t)r * 256 + f];
    s += v; s2 += v * v;
  }
  atomicAdd(&sum[f], s);
  atomicAdd(&sumsq[f], s2);
}

// BN + ELU, emits bf16 directly (A operand of the W2 MFMA GEMM)
__global__ __launch_bounds__(256) void bn_apply_bf16(
    const float* __restrict__ x, const float* __restrict__ sum, const float* __restrict__ sumsq,
    const float* __restrict__ gamma, const float* __restrict__ beta, ushort* __restrict__ o) {
  size_t i = (size_t)blockIdx.x * 256 + threadIdx.x;
  if (i >= (size_t)N_NODES * 256) return;
  int f = (int)(i & 255);
  const float invN = 1.0f / N_NODES;
  float mu = sum[f] * invN;
  float var = sumsq[f] * invN - mu * mu;
  float v = (x[i] - mu) * rsqrtf(var + EPS) * gamma[f] + beta[f];
  float e = v > 0.f ? v : expf(v) - 1.0f;
  o[i] = f2bf(e);
}

extern "C" void kernel_launch(void* const* d_in, const int* in_sizes, int n_in,
                              void* d_out, int out_size, void* d_ws, size_t ws_size,
                              hipStream_t stream) {
  const float* x     = (const float*)d_in[0];
  const int*   ei    = (const int*)d_in[1];
  const float* dw    = (const float*)d_in[2];
  const float* W1    = (const float*)d_in[3];
  const float* as1   = (const float*)d_in[4];
  const float* ad1   = (const float*)d_in[5];
  // d_in[6] = b1: cancels through BatchNorm
  const float* gamma = (const float*)d_in[7];
  const float* beta  = (const float*)d_in[8];
  const float* W2    = (const float*)d_in[9];
  const float* as2   = (const float*)d_in[10];
  const float* ad2   = (const float*)d_in[11];
  const float* b2    = (const float*)d_in[12];
  const float* Wg1   = (const float*)d_in[13];
  const float* bg1   = (const float*)d_in[14];
  const float* Wg2   = (const float*)d_in[15];
  const float* bg2   = (const float*)d_in[16];
  float* out = (float*)d_out;

  char* p = (char*)d_ws;
  size_t off = 0;
  auto alloc = [&](size_t bytes) {
    char* r = p + off;
    off = (off + bytes + 255) & ~(size_t)255;
    return r;
  };
  float*  bufA  = (float*)alloc((size_t)N_NODES * 256 * 4);   // h1 -> h2
  float*  bufB  = (float*)alloc((size_t)N_NODES * 256 * 4);   // agg1 -> g1,g,g2 slots
  float*  bufC  = (float*)alloc((size_t)N_NODES * 64 * 4);    // h_gat
  ushort* xbf   = (ushort*)alloc((size_t)M_PAD * 256 * 2);    // x_bf16 [M_PAD,128] then hbn_bf16 [M_PAD,256]
  ushort* w1t   = (ushort*)alloc((size_t)256 * 128 * 2);
  ushort* w2t   = (ushort*)alloc((size_t)256 * 256 * 2);
  float*  ssrc1 = (float*)alloc((size_t)N_NODES * 4 * 4);
  float*  sdst1 = (float*)alloc((size_t)N_NODES * 4 * 4);
  float*  ssrc2 = (float*)alloc((size_t)N_NODES * 4 * 4);
  float*  sdst2 = (float*)alloc((size_t)N_NODES * 4 * 4);
  int*    degi  = (int*)alloc((size_t)N_NODES * 4);
  int*    rowst = (int*)alloc((size_t)N_NODES * 4);
  int*    cursor= (int*)alloc((size_t)N_NODES * 4);
  int*    bsum  = (int*)alloc(SCAN_BLOCKS * 4);
  float*  dinv  = (float*)alloc((size_t)N_NODES * 4);
  int*    csr   = (int*)alloc((size_t)ETOT * 4);
  float*  bnsum = (float*)alloc(256 * 4);
  float*  bnsq  = (float*)alloc(256 * 4);

  const dim3 blk(256);
  const int egrid = (ETOT + 255) / 256;
  const int ngrid = 12500;

  hipMemsetAsync(degi, 0, (size_t)N_NODES * 4, stream);
  hipMemsetAsync(bnsum, 0, 256 * 4, stream);
  hipMemsetAsync(bnsq, 0, 256 * 4, stream);
  // zero hbn pad rows (beyond x_bf16's extent, so safe to do now)
  hipMemsetAsync(xbf + (size_t)N_NODES * 256, 0, (size_t)(M_PAD - N_NODES) * 256 * 2, stream);

  // ---- CSR build + bf16 prep ----
  deg_count_int<<<egrid, blk, 0, stream>>>(ei, degi);
  scan1<<<SCAN_BLOCKS, blk, 0, stream>>>(degi, rowst, bsum);
  scan2<<<1, blk, 0, stream>>>(bsum);
  scan3<<<SCAN_BLOCKS, blk, 0, stream>>>(rowst, bsum, cursor, degi, dinv);
  scatter_k<<<egrid, blk, 0, stream>>>(ei, cursor, csr);
  cast_x_bf16<<<(M_PAD * 32 + 255) / 256, blk, 0, stream>>>(x, xbf);
  tcast_w<<<(128 * 256 + 255) / 256, blk, 0, stream>>>(W1, w1t, 128, 256);
  tcast_w<<<(256 * 256 + 255) / 256, blk, 0, stream>>>(W2, w2t, 256, 256);

  // ---- GAT layer 1 ----
  gemm_bf16<128><<<dim3(782, 4), blk, 0, stream>>>(xbf, w1t, bufA, N_NODES, 256);  // h1
  attn_scores<<<ngrid, blk, 0, stream>>>(bufA, as1, ad1, ssrc1, sdst1);
  gat_agg1_csr<<<ngrid, blk, 0, stream>>>(rowst, degi, csr, bufA, ssrc1, sdst1, bufB);

  // ---- BatchNorm + ELU (-> bf16 A operand for W2 GEMM; reuses xbf region) ----
  bn_stats<<<(N_NODES + 63) / 64, blk, 0, stream>>>(bufB, bnsum, bnsq);
  bn_apply_bf16<<<(int)(((size_t)N_NODES * 256 + 255) / 256), blk, 0, stream>>>(
      bufB, bnsum, bnsq, gamma, beta, xbf);

  // ---- GAT layer 2 ----
  gemm_bf16<256><<<dim3(782, 4), blk, 0, stream>>>(xbf, w2t, bufA, N_NODES, 256);  // h2
  attn_scores<<<ngrid, blk, 0, stream>>>(bufA, as2, ad2, ssrc2, sdst2);
  gat_agg2_csr<<<ngrid, blk, 0, stream>>>(rowst, degi, csr, bufA, ssrc2, sdst2, bufC);

  // ---- GCN branch (fp32; bufB slots: 0=g1, 1=g, 2=g2) ----
  float* g1 = bufB;
  float* g  = bufB + (size_t)N_NODES * 64;
  float* g2 = bufB + (size_t)N_NODES * 128;
  gemm_f32<<<dim3(782, 1), blk, 0, stream>>>(x, Wg1, g1, N_NODES, 64, 128);
  gcn_agg_relu<<<ngrid, blk, 0, stream>>>(rowst, degi, csr, g1, dinv, bg1, g);
  gemm_f32<<<dim3(782, 1), blk, 0, stream>>>(g, Wg2, g2, N_NODES, 64, 64);
  gcn_agg_fuse<<<ngrid, blk, 0, stream>>>(rowst, degi, csr, g2, dinv, bg2, bufC, b2, dw, out);
}

// Round 6
// 602.762 us; speedup vs baseline: 5.8665x; 1.1086x over previous
//
#include <hip/hip_runtime.h>

#define N_NODES 50000
#define M_PAD   50048    // 782 * 64, zero-padded rows for MFMA tile staging
#define N_EDGES 600000
#define ETOT    650000   // N_EDGES + N_NODES self loops
#define EPS     1e-5f
#define SCAN_BLOCKS 196  // ceil(50000/256)

typedef short bf16x8 __attribute__((ext_vector_type(8)));
typedef float f32x4  __attribute__((ext_vector_type(4)));

static __device__ __forceinline__ float leaky(float v) { return v >= 0.f ? v : 0.2f * v; }

// round-to-nearest-even float -> bf16 bits
static __device__ __forceinline__ ushort f2bf(float f) {
  unsigned u = __float_as_uint(f);
  return (ushort)((u + 0x7fff + ((u >> 16) & 1)) >> 16);
}
static __device__ __forceinline__ float bf2f(ushort u) {
  return __uint_as_float(((unsigned)u) << 16);
}

// ---------------------------------------------------------------------------
// bf16 MFMA GEMM: C[M,Nfull] = A[M_PAD,K]bf16 @ Bt[Nfull,K]bf16^T.
// 64x64 tile, BK=64, 4 waves each computing a 32x32 quadrant via 16x16x32 MFMA.
// LDS XOR-swizzle (byte ^= (row&7)<<4) keeps fragment ds_read_b128 2-way max.
// OUTBF: emit bf16 (ushort) else fp32.
// ---------------------------------------------------------------------------
template <int K, bool OUTBF>
__global__ __launch_bounds__(256) void gemm_bf16(
    const ushort* __restrict__ A, const ushort* __restrict__ Bt,
    void* __restrict__ C, int M, int Nfull) {
  __shared__ char As[64 * 128];   // 64 rows x 64 bf16 (128B)
  __shared__ char Bs[64 * 128];
  const int tid = threadIdx.x;
  const int w = tid >> 6, lane = tid & 63;
  const int wr = w >> 1, wc = w & 1;
  const int m0 = blockIdx.x * 64, n0 = blockIdx.y * 64;

  f32x4 acc[2][2] = {};

  for (int k0 = 0; k0 < K; k0 += 64) {
    __syncthreads();
#pragma unroll
    for (int j = 0; j < 2; ++j) {
      int i = tid + j * 256;               // 0..511 chunk id (16B chunks)
      int row = i >> 3;
      int cb = (i & 7) * 16;               // byte within 128B row
      int dst = row * 128 + (cb ^ ((row & 7) << 4));
      uint4 va = *(const uint4*)((const char*)A + ((size_t)(m0 + row) * K + k0) * 2 + cb);
      *(uint4*)(As + dst) = va;
      uint4 vb = *(const uint4*)((const char*)Bt + ((size_t)(n0 + row) * K + k0) * 2 + cb);
      *(uint4*)(Bs + dst) = vb;
    }
    __syncthreads();
#pragma unroll
    for (int c = 0; c < 2; ++c) {
      bf16x8 af[2], bfr[2];
      int kb = (lane >> 4) * 16 + c * 64;
#pragma unroll
      for (int m = 0; m < 2; ++m) {
        int lr = wr * 32 + m * 16 + (lane & 15);
        af[m] = *(const bf16x8*)(As + lr * 128 + (kb ^ ((lr & 7) << 4)));
      }
#pragma unroll
      for (int n = 0; n < 2; ++n) {
        int lr = wc * 32 + n * 16 + (lane & 15);
        bfr[n] = *(const bf16x8*)(Bs + lr * 128 + (kb ^ ((lr & 7) << 4)));
      }
#pragma unroll
      for (int m = 0; m < 2; ++m)
#pragma unroll
        for (int n = 0; n < 2; ++n)
          acc[m][n] = __builtin_amdgcn_mfma_f32_16x16x32_bf16(af[m], bfr[n], acc[m][n], 0, 0, 0);
    }
  }
#pragma unroll
  for (int m = 0; m < 2; ++m)
#pragma unroll
    for (int n = 0; n < 2; ++n)
#pragma unroll
      for (int i = 0; i < 4; ++i) {
        int row = m0 + wr * 32 + m * 16 + (lane >> 4) * 4 + i;
        int col = n0 + wc * 32 + n * 16 + (lane & 15);
        if (row < M) {
          if (OUTBF) ((ushort*)C)[(size_t)row * Nfull + col] = f2bf(acc[m][n][i]);
          else       ((float*)C)[(size_t)row * Nfull + col] = acc[m][n][i];
        }
      }
}

// cast x (fp32 [N_NODES,128]) -> bf16 [M_PAD,128], pad rows zeroed.
__global__ __launch_bounds__(256) void cast_x_bf16(const float* __restrict__ x, ushort* __restrict__ o) {
  int i = blockIdx.x * 256 + threadIdx.x;          // chunk of 4
  if (i >= M_PAD * 32) return;
  int i4 = i * 4;
  int row = i4 >> 7;
  ushort4 r;
  if (row < N_NODES) {
    const float4 v = *(const float4*)(x + i4);
    r.x = f2bf(v.x); r.y = f2bf(v.y); r.z = f2bf(v.z); r.w = f2bf(v.w);
  } else {
    r.x = r.y = r.z = r.w = 0;
  }
  *(ushort4*)(o + i4) = r;
}

// transpose-cast weights: W[K,N] fp32 -> Wt[N,K] bf16
__global__ __launch_bounds__(256) void tcast_w(const float* __restrict__ W, ushort* __restrict__ Wt,
                                               int K, int N) {
  int i = blockIdx.x * 256 + threadIdx.x;
  if (i >= K * N) return;
  int k = i / N, n = i - k * N;
  Wt[n * K + k] = f2bf(W[i]);
}

// ---------------------------------------------------------------------------
// Per-node attention scores on bf16 h (wave per row; 16-lane group = one head)
// ---------------------------------------------------------------------------
__global__ __launch_bounds__(256) void attn_scores_bf(
    const ushort* __restrict__ h, const float* __restrict__ a_src,
    const float* __restrict__ a_dst, float* __restrict__ ssrc, float* __restrict__ sdst) {
  const int wave = threadIdx.x >> 6, lane = threadIdx.x & 63;
  const int row = blockIdx.x * 4 + wave;
  if (row >= N_NODES) return;
  const ushort4 hv = *(const ushort4*)(h + (size_t)row * 256 + lane * 4);
  float h0 = bf2f(hv.x), h1 = bf2f(hv.y), h2 = bf2f(hv.z), h3 = bf2f(hv.w);
  const float4 as = *(const float4*)(a_src + lane * 4);
  const float4 ad = *(const float4*)(a_dst + lane * 4);
  float ps = h0 * as.x + h1 * as.y + h2 * as.z + h3 * as.w;
  float pd = h0 * ad.x + h1 * ad.y + h2 * ad.z + h3 * ad.w;
#pragma unroll
  for (int off = 1; off < 16; off <<= 1) {
    ps += __shfl_xor(ps, off);
    pd += __shfl_xor(pd, off);
  }
  if ((lane & 15) == 0) {
    int hh = lane >> 4;
    ssrc[row * 4 + hh] = ps;
    sdst[row * 4 + hh] = pd;
  }
}

// ---------------------------------------------------------------------------
// CSR build
// ---------------------------------------------------------------------------
static __device__ __forceinline__ void edge_sd(const int* ei, int e, int& src, int& dst) {
  if (e < N_EDGES) { src = ei[e]; dst = ei[N_EDGES + e]; }
  else             { src = dst = e - N_EDGES; }
}

__global__ __launch_bounds__(256) void deg_count_int(const int* __restrict__ ei, int* __restrict__ degi) {
  int e = blockIdx.x * 256 + threadIdx.x;
  if (e >= ETOT) return;
  int dst = (e < N_EDGES) ? ei[N_EDGES + e] : (e - N_EDGES);
  atomicAdd(&degi[dst], 1);
}

__global__ __launch_bounds__(256) void scan1(const int* __restrict__ degi,
                                             int* __restrict__ partial, int* __restrict__ bsum) {
  __shared__ int sm[256];
  int i = blockIdx.x * 256 + threadIdx.x;
  int v = (i < N_NODES) ? degi[i] : 0;
  sm[threadIdx.x] = v;
  __syncthreads();
#pragma unroll
  for (int off = 1; off < 256; off <<= 1) {
    int t = (threadIdx.x >= off) ? sm[threadIdx.x - off] : 0;
    __syncthreads();
    sm[threadIdx.x] += t;
    __syncthreads();
  }
  if (i < N_NODES) partial[i] = sm[threadIdx.x] - v;
  if (threadIdx.x == 255) bsum[blockIdx.x] = sm[255];
}

__global__ __launch_bounds__(256) void scan2(int* __restrict__ bsum) {
  __shared__ int sm[256];
  int v = (threadIdx.x < SCAN_BLOCKS) ? bsum[threadIdx.x] : 0;
  sm[threadIdx.x] = v;
  __syncthreads();
#pragma unroll
  for (int off = 1; off < 256; off <<= 1) {
    int t = (threadIdx.x >= off) ? sm[threadIdx.x - off] : 0;
    __syncthreads();
    sm[threadIdx.x] += t;
    __syncthreads();
  }
  if (threadIdx.x < SCAN_BLOCKS) bsum[threadIdx.x] = sm[threadIdx.x] - v;
}

__global__ __launch_bounds__(256) void scan3(int* __restrict__ rowstart, const int* __restrict__ bsum,
                                             int* __restrict__ cursor, const int* __restrict__ degi,
                                             float* __restrict__ dinv) {
  int i = blockIdx.x * 256 + threadIdx.x;
  if (i >= N_NODES) return;
  int r = rowstart[i] + bsum[blockIdx.x];
  rowstart[i] = r;
  cursor[i] = r;
  dinv[i] = rsqrtf(fmaxf((float)degi[i], 1.0f));
}

__global__ __launch_bounds__(256) void scatter_k(const int* __restrict__ ei,
                                                 int* __restrict__ cursor, int* __restrict__ csr) {
  int e = blockIdx.x * 256 + threadIdx.x;
  if (e >= ETOT) return;
  int src, dst; edge_sd(ei, e, src, dst);
  int pos = atomicAdd(&cursor[dst], 1);
  csr[pos] = src;
}

// ---------------------------------------------------------------------------
// GAT aggregations over bf16 features (gather, online softmax; logits bounded)
// ---------------------------------------------------------------------------
__global__ __launch_bounds__(256) void gat_agg1_bf(
    const int* __restrict__ rowstart, const int* __restrict__ degi, const int* __restrict__ csr,
    const ushort* __restrict__ h, const float* __restrict__ ssrc, const float* __restrict__ sdst,
    float* __restrict__ outp) {
  int dst = blockIdx.x * 4 + (threadIdx.x >> 6);
  if (dst >= N_NODES) return;
  int lane = threadIdx.x & 63;
  int hh = lane >> 4;
  int rs = rowstart[dst], re = rs + degi[dst];
  float sd = sdst[dst * 4 + hh];
  float z = 0.f;
  float ax = 0.f, ay = 0.f, az = 0.f, aw = 0.f;
  for (int j = rs; j < re; ++j) {
    int src = csr[j];
    float p = __expf(leaky(ssrc[src * 4 + hh] + sd));
    z += p;
    const ushort4 hv = *(const ushort4*)(h + (size_t)src * 256 + lane * 4);
    ax += p * bf2f(hv.x); ay += p * bf2f(hv.y); az += p * bf2f(hv.z); aw += p * bf2f(hv.w);
  }
  float inv = 1.f / z;
  float4 o = { ax * inv, ay * inv, az * inv, aw * inv };
  *(float4*)(outp + (size_t)dst * 256 + lane * 4) = o;
}

__global__ __launch_bounds__(256) void gat_agg2_bf(
    const int* __restrict__ rowstart, const int* __restrict__ degi, const int* __restrict__ csr,
    const ushort* __restrict__ h2, const float* __restrict__ ssrc, const float* __restrict__ sdst,
    float* __restrict__ outp) {
  int dst = blockIdx.x * 4 + (threadIdx.x >> 6);
  if (dst >= N_NODES) return;
  int lane = threadIdx.x & 63;
  int rs = rowstart[dst], re = rs + degi[dst];
  const float4 sd = *(const float4*)(sdst + dst * 4);
  float z0 = 0.f, z1 = 0.f, z2 = 0.f, z3 = 0.f;
  float a0 = 0.f, a1 = 0.f, a2 = 0.f, a3 = 0.f;
  for (int j = rs; j < re; ++j) {
    int src = csr[j];
    const float4 ss = *(const float4*)(ssrc + src * 4);
    float p0 = __expf(leaky(ss.x + sd.x));
    float p1 = __expf(leaky(ss.y + sd.y));
    float p2 = __expf(leaky(ss.z + sd.z));
    float p3 = __expf(leaky(ss.w + sd.w));
    z0 += p0; z1 += p1; z2 += p2; z3 += p3;
    const ushort* hb = h2 + (size_t)src * 256;
    a0 += p0 * bf2f(hb[lane]);
    a1 += p1 * bf2f(hb[64 + lane]);
    a2 += p2 * bf2f(hb[128 + lane]);
    a3 += p3 * bf2f(hb[192 + lane]);
  }
  outp[(size_t)dst * 64 + lane] = 0.25f * (a0 / z0 + a1 / z1 + a2 / z2 + a3 / z3);
}

// GCN layer-1 aggregation + bias + ReLU; bf16 in (g1), bf16 out (A operand of GEMM2)
__global__ __launch_bounds__(256) void gcn_agg_relu_bf(
    const int* __restrict__ rowstart, const int* __restrict__ degi, const int* __restrict__ csr,
    const ushort* __restrict__ g, const float* __restrict__ dinv, const float* __restrict__ bias,
    ushort* __restrict__ outp) {
  int dst = blockIdx.x * 4 + (threadIdx.x >> 6);
  if (dst >= N_NODES) return;
  int lane = threadIdx.x & 63;
  int rs = rowstart[dst], re = rs + degi[dst];
  float acc = 0.f;
  for (int j = rs; j < re; ++j) {
    int src = csr[j];
    acc += dinv[src] * bf2f(g[(size_t)src * 64 + lane]);
  }
  float v = acc * dinv[dst] + bias[lane];
  outp[(size_t)dst * 64 + lane] = f2bf(fmaxf(v, 0.f));
}

// GCN layer-2 aggregation (bf16 g2) + bias, fused with drift-weighted combine
__global__ __launch_bounds__(256) void gcn_agg_fuse_bf(
    const int* __restrict__ rowstart, const int* __restrict__ degi, const int* __restrict__ csr,
    const ushort* __restrict__ g2, const float* __restrict__ dinv, const float* __restrict__ bg2,
    const float* __restrict__ hgat, const float* __restrict__ b2, const float* __restrict__ dw,
    float* __restrict__ outp) {
  int dst = blockIdx.x * 4 + (threadIdx.x >> 6);
  if (dst >= N_NODES) return;
  int lane = threadIdx.x & 63;
  int rs = rowstart[dst], re = rs + degi[dst];
  float acc = 0.f;
  for (int j = rs; j < re; ++j) {
    int src = csr[j];
    acc += dinv[src] * bf2f(g2[(size_t)src * 64 + lane]);
  }
  float w = dw[0];
  float gcn = acc * dinv[dst] + bg2[lane];
  float gat = hgat[(size_t)dst * 64 + lane] + b2[lane];
  outp[(size_t)dst * 64 + lane] = w * gat + (1.f - w) * gcn;
}

// ---------------------------------------------------------------------------
// BatchNorm
// ---------------------------------------------------------------------------
__global__ __launch_bounds__(256) void bn_stats(
    const float* __restrict__ x, float* __restrict__ sum, float* __restrict__ sumsq) {
  int f = threadIdx.x;
  int r0 = blockIdx.x * 64;
  int rend = min(r0 + 64, N_NODES);
  float s = 0.f, s2 = 0.f;
  for (int r = r0; r < rend; ++r) {
    float v = x[(size_t)r * 256 + f];
    s += v; s2 += v * v;
  }
  atomicAdd(&sum[f], s);
  atomicAdd(&sumsq[f], s2);
}

// BN + ELU, emits bf16 directly (A operand of the W2 MFMA GEMM)
__global__ __launch_bounds__(256) void bn_apply_bf16(
    const float* __restrict__ x, const float* __restrict__ sum, const float* __restrict__ sumsq,
    const float* __restrict__ gamma, const float* __restrict__ beta, ushort* __restrict__ o) {
  size_t i = (size_t)blockIdx.x * 256 + threadIdx.x;
  if (i >= (size_t)N_NODES * 256) return;
  int f = (int)(i & 255);
  const float invN = 1.0f / N_NODES;
  float mu = sum[f] * invN;
  float var = sumsq[f] * invN - mu * mu;
  float v = (x[i] - mu) * rsqrtf(var + EPS) * gamma[f] + beta[f];
  float e = v > 0.f ? v : expf(v) - 1.0f;
  o[i] = f2bf(e);
}

extern "C" void kernel_launch(void* const* d_in, const int* in_sizes, int n_in,
                              void* d_out, int out_size, void* d_ws, size_t ws_size,
                              hipStream_t stream) {
  const float* x     = (const float*)d_in[0];
  const int*   ei    = (const int*)d_in[1];
  const float* dw    = (const float*)d_in[2];
  const float* W1    = (const float*)d_in[3];
  const float* as1   = (const float*)d_in[4];
  const float* ad1   = (const float*)d_in[5];
  // d_in[6] = b1: cancels through BatchNorm
  const float* gamma = (const float*)d_in[7];
  const float* beta  = (const float*)d_in[8];
  const float* W2    = (const float*)d_in[9];
  const float* as2   = (const float*)d_in[10];
  const float* ad2   = (const float*)d_in[11];
  const float* b2    = (const float*)d_in[12];
  const float* Wg1   = (const float*)d_in[13];
  const float* bg1   = (const float*)d_in[14];
  const float* Wg2   = (const float*)d_in[15];
  const float* bg2   = (const float*)d_in[16];
  float* out = (float*)d_out;

  char* p = (char*)d_ws;
  size_t off = 0;
  auto alloc = [&](size_t bytes) {
    char* r = p + off;
    off = (off + bytes + 255) & ~(size_t)255;
    return r;
  };
  float*  bufB  = (float*)alloc((size_t)N_NODES * 256 * 4);   // agg1 fp32; later overlaid by h2bf
  float*  bufC  = (float*)alloc((size_t)N_NODES * 64 * 4);    // h_gat fp32
  ushort* xbf   = (ushort*)alloc((size_t)M_PAD * 128 * 2);    // x bf16 (GEMM-A, padded)
  ushort* R1    = (ushort*)alloc((size_t)M_PAD * 256 * 2);    // h1bf, then hbn bf16 (GEMM-A, padded)
  ushort* g1bf  = (ushort*)alloc((size_t)N_NODES * 64 * 2);
  ushort* gbf   = (ushort*)alloc((size_t)M_PAD * 64 * 2);     // relu(g) bf16 (GEMM-A, padded)
  ushort* g2bf  = (ushort*)alloc((size_t)N_NODES * 64 * 2);
  ushort* w1t   = (ushort*)alloc((size_t)256 * 128 * 2);
  ushort* w2t   = (ushort*)alloc((size_t)256 * 256 * 2);
  ushort* wg1t  = (ushort*)alloc((size_t)64 * 128 * 2);
  ushort* wg2t  = (ushort*)alloc((size_t)64 * 64 * 2);
  float*  ssrc1 = (float*)alloc((size_t)N_NODES * 4 * 4);
  float*  sdst1 = (float*)alloc((size_t)N_NODES * 4 * 4);
  float*  ssrc2 = (float*)alloc((size_t)N_NODES * 4 * 4);
  float*  sdst2 = (float*)alloc((size_t)N_NODES * 4 * 4);
  int*    degi  = (int*)alloc((size_t)N_NODES * 4);
  int*    rowst = (int*)alloc((size_t)N_NODES * 4);
  int*    cursor= (int*)alloc((size_t)N_NODES * 4);
  int*    bsum  = (int*)alloc(SCAN_BLOCKS * 4);
  float*  dinv  = (float*)alloc((size_t)N_NODES * 4);
  int*    csr   = (int*)alloc((size_t)ETOT * 4);
  float*  bnsum = (float*)alloc(256 * 4);
  float*  bnsq  = (float*)alloc(256 * 4);
  ushort* h2bf  = (ushort*)bufB;   // overlay: bufB fp32 dead after bn_apply

  const dim3 blk(256);
  const int egrid = (ETOT + 255) / 256;
  const int ngrid = 12500;

  hipMemsetAsync(degi, 0, (size_t)N_NODES * 4, stream);
  hipMemsetAsync(bnsum, 0, 256 * 4, stream);
  hipMemsetAsync(bnsq, 0, 256 * 4, stream);
  // zero GEMM-A pad rows (row-guarded writes never touch them afterwards)
  hipMemsetAsync(R1 + (size_t)N_NODES * 256, 0, (size_t)(M_PAD - N_NODES) * 256 * 2, stream);
  hipMemsetAsync(gbf + (size_t)N_NODES * 64, 0, (size_t)(M_PAD - N_NODES) * 64 * 2, stream);

  // ---- CSR build + bf16 prep ----
  deg_count_int<<<egrid, blk, 0, stream>>>(ei, degi);
  scan1<<<SCAN_BLOCKS, blk, 0, stream>>>(degi, rowst, bsum);
  scan2<<<1, blk, 0, stream>>>(bsum);
  scan3<<<SCAN_BLOCKS, blk, 0, stream>>>(rowst, bsum, cursor, degi, dinv);
  scatter_k<<<egrid, blk, 0, stream>>>(ei, cursor, csr);
  cast_x_bf16<<<(M_PAD * 32 + 255) / 256, blk, 0, stream>>>(x, xbf);
  tcast_w<<<(128 * 256 + 255) / 256, blk, 0, stream>>>(W1, w1t, 128, 256);
  tcast_w<<<(256 * 256 + 255) / 256, blk, 0, stream>>>(W2, w2t, 256, 256);
  tcast_w<<<(128 * 64 + 255) / 256, blk, 0, stream>>>(Wg1, wg1t, 128, 64);
  tcast_w<<<(64 * 64 + 255) / 256, blk, 0, stream>>>(Wg2, wg2t, 64, 64);

  // ---- GEMMs off x (xbf dead after these) ----
  gemm_bf16<128, true><<<dim3(782, 4), blk, 0, stream>>>(xbf, w1t, R1, N_NODES, 256);    // h1 bf16
  gemm_bf16<128, true><<<dim3(782, 1), blk, 0, stream>>>(xbf, wg1t, g1bf, N_NODES, 64);  // g1 bf16

  // ---- GAT layer 1 ----
  attn_scores_bf<<<ngrid, blk, 0, stream>>>(R1, as1, ad1, ssrc1, sdst1);
  gat_agg1_bf<<<ngrid, blk, 0, stream>>>(rowst, degi, csr, R1, ssrc1, sdst1, bufB);

  // ---- GCN layer 1 (independent) ----
  gcn_agg_relu_bf<<<ngrid, blk, 0, stream>>>(rowst, degi, csr, g1bf, dinv, bg1, gbf);
  gemm_bf16<64, true><<<dim3(782, 1), blk, 0, stream>>>(gbf, wg2t, g2bf, N_NODES, 64);   // g2 bf16

  // ---- BatchNorm + ELU -> hbn bf16 (reuses R1; h1bf dead) ----
  bn_stats<<<(N_NODES + 63) / 64, blk, 0, stream>>>(bufB, bnsum, bnsq);
  bn_apply_bf16<<<(int)(((size_t)N_NODES * 256 + 255) / 256), blk, 0, stream>>>(
      bufB, bnsum, bnsq, gamma, beta, R1);

  // ---- GAT layer 2 (h2bf overlays bufB; fp32 agg1 dead after bn_apply) ----
  gemm_bf16<256, true><<<dim3(782, 4), blk, 0, stream>>>(R1, w2t, h2bf, N_NODES, 256);   // h2 bf16
  attn_scores_bf<<<ngrid, blk, 0, stream>>>(h2bf, as2, ad2, ssrc2, sdst2);
  gat_agg2_bf<<<ngrid, blk, 0, stream>>>(rowst, degi, csr, h2bf, ssrc2, sdst2, bufC);

  // ---- GCN layer 2 + drift-weighted fusion ----
  gcn_agg_fuse_bf<<<ngrid, blk, 0, stream>>>(rowst, degi, csr, g2bf, dinv, bg2, bufC, b2, dw, out);
}

// Round 10
// 559.943 us; speedup vs baseline: 6.3151x; 1.0765x over previous
//
#include <hip/hip_runtime.h>

#define N_NODES 50000
#define M_PAD   50048    // 782 * 64, zero-padded rows for MFMA tile staging
#define N_EDGES 600000
#define ETOT    650000   // N_EDGES + N_NODES self loops
#define EPS     1e-5f
#define SCAN_BLOCKS 196  // ceil(50000/256)

typedef short bf16x8 __attribute__((ext_vector_type(8)));
typedef float f32x4  __attribute__((ext_vector_type(4)));

static __device__ __forceinline__ float leaky(float v) { return v >= 0.f ? v : 0.2f * v; }

// round-to-nearest-even float -> bf16 bits
static __device__ __forceinline__ ushort f2bf(float f) {
  unsigned u = __float_as_uint(f);
  return (ushort)((u + 0x7fff + ((u >> 16) & 1)) >> 16);
}
static __device__ __forceinline__ float bf2f(ushort u) {
  return __uint_as_float(((unsigned)u) << 16);
}

// ---------------------------------------------------------------------------
// bf16 MFMA GEMM: C[M,Nfull] = A[M_PAD,K]bf16 @ Bt[Nfull,K]bf16^T.
// 64x64 tile, BK=64, 4 waves each computing a 32x32 quadrant via 16x16x32 MFMA.
// LDS XOR-swizzle (byte ^= (row&7)<<4) keeps fragment ds_read_b128 2-way max.
// OUTBF: emit bf16. PERM (requires OUTBF && Nfull==256): head-interleaved
// output layout col -> (col&63)*4 + (col>>6), i.e. hp[row][c*4+h].
// ---------------------------------------------------------------------------
template <int K, bool OUTBF, bool PERM>
__global__ __launch_bounds__(256) void gemm_bf16(
    const ushort* __restrict__ A, const ushort* __restrict__ Bt,
    void* __restrict__ C, int M, int Nfull) {
  __shared__ char As[64 * 128];   // 64 rows x 64 bf16 (128B)
  __shared__ char Bs[64 * 128];
  const int tid = threadIdx.x;
  const int w = tid >> 6, lane = tid & 63;
  const int wr = w >> 1, wc = w & 1;
  const int m0 = blockIdx.x * 64, n0 = blockIdx.y * 64;

  f32x4 acc[2][2] = {};

  for (int k0 = 0; k0 < K; k0 += 64) {
    __syncthreads();
#pragma unroll
    for (int j = 0; j < 2; ++j) {
      int i = tid + j * 256;               // 0..511 chunk id (16B chunks)
      int row = i >> 3;
      int cb = (i & 7) * 16;               // byte within 128B row
      int dst = row * 128 + (cb ^ ((row & 7) << 4));
      uint4 va = *(const uint4*)((const char*)A + ((size_t)(m0 + row) * K + k0) * 2 + cb);
      *(uint4*)(As + dst) = va;
      uint4 vb = *(const uint4*)((const char*)Bt + ((size_t)(n0 + row) * K + k0) * 2 + cb);
      *(uint4*)(Bs + dst) = vb;
    }
    __syncthreads();
#pragma unroll
    for (int c = 0; c < 2; ++c) {
      bf16x8 af[2], bfr[2];
      int kb = (lane >> 4) * 16 + c * 64;
#pragma unroll
      for (int m = 0; m < 2; ++m) {
        int lr = wr * 32 + m * 16 + (lane & 15);
        af[m] = *(const bf16x8*)(As + lr * 128 + (kb ^ ((lr & 7) << 4)));
      }
#pragma unroll
      for (int n = 0; n < 2; ++n) {
        int lr = wc * 32 + n * 16 + (lane & 15);
        bfr[n] = *(const bf16x8*)(Bs + lr * 128 + (kb ^ ((lr & 7) << 4)));
      }
#pragma unroll
      for (int m = 0; m < 2; ++m)
#pragma unroll
        for (int n = 0; n < 2; ++n)
          acc[m][n] = __builtin_amdgcn_mfma_f32_16x16x32_bf16(af[m], bfr[n], acc[m][n], 0, 0, 0);
    }
  }
#pragma unroll
  for (int m = 0; m < 2; ++m)
#pragma unroll
    for (int n = 0; n < 2; ++n)
#pragma unroll
      for (int i = 0; i < 4; ++i) {
        int row = m0 + wr * 32 + m * 16 + (lane >> 4) * 4 + i;
        int col = n0 + wc * 32 + n * 16 + (lane & 15);
        if (row < M) {
          if (OUTBF) {
            int oc = PERM ? (((col & 63) << 2) | (col >> 6)) : col;
            ((ushort*)C)[(size_t)row * Nfull + oc] = f2bf(acc[m][n][i]);
          } else {
            ((float*)C)[(size_t)row * Nfull + col] = acc[m][n][i];
          }
        }
      }
}

// cast x (fp32 [N_NODES,128]) -> bf16 [M_PAD,128], pad rows zeroed.
__global__ __launch_bounds__(256) void cast_x_bf16(const float* __restrict__ x, ushort* __restrict__ o) {
  int i = blockIdx.x * 256 + threadIdx.x;          // chunk of 4
  if (i >= M_PAD * 32) return;
  int i4 = i * 4;
  int row = i4 >> 7;
  ushort4 r;
  if (row < N_NODES) {
    const float4 v = *(const float4*)(x + i4);
    r.x = f2bf(v.x); r.y = f2bf(v.y); r.z = f2bf(v.z); r.w = f2bf(v.w);
  } else {
    r.x = r.y = r.z = r.w = 0;
  }
  *(ushort4*)(o + i4) = r;
}

// transpose-cast weights: W[K,N] fp32 -> Wt[N,K] bf16
__global__ __launch_bounds__(256) void tcast_w(const float* __restrict__ W, ushort* __restrict__ Wt,
                                               int K, int N) {
  int i = blockIdx.x * 256 + threadIdx.x;
  if (i >= K * N) return;
  int k = i / N, n = i - k * N;
  Wt[n * K + k] = f2bf(W[i]);
}

// ---------------------------------------------------------------------------
// Attention scores, standard layout h[row][h*64+c] (wave/row; 16-lane grp = head)
// ---------------------------------------------------------------------------
__global__ __launch_bounds__(256) void attn_scores_bf(
    const ushort* __restrict__ h, const float* __restrict__ a_src,
    const float* __restrict__ a_dst, float* __restrict__ ssrc, float* __restrict__ sdst) {
  const int wave = threadIdx.x >> 6, lane = threadIdx.x & 63;
  const int row = blockIdx.x * 4 + wave;
  if (row >= N_NODES) return;
  const ushort4 hv = *(const ushort4*)(h + (size_t)row * 256 + lane * 4);
  float h0 = bf2f(hv.x), h1 = bf2f(hv.y), h2 = bf2f(hv.z), h3 = bf2f(hv.w);
  const float4 as = *(const float4*)(a_src + lane * 4);
  const float4 ad = *(const float4*)(a_dst + lane * 4);
  float ps = h0 * as.x + h1 * as.y + h2 * as.z + h3 * as.w;
  float pd = h0 * ad.x + h1 * ad.y + h2 * ad.z + h3 * ad.w;
#pragma unroll
  for (int off = 1; off < 16; off <<= 1) {
    ps += __shfl_xor(ps, off);
    pd += __shfl_xor(pd, off);
  }
  if ((lane & 15) == 0) {
    int hh = lane >> 4;
    ssrc[row * 4 + hh] = ps;
    sdst[row * 4 + hh] = pd;
  }
}

// Attention scores, permuted layout hp[row][c*4+h]. Lane c holds heads 0..3 at
// col c; 4 head-sums reduced across the full wave.
__global__ __launch_bounds__(256) void attn_scores_perm(
    const ushort* __restrict__ hp, const float* __restrict__ a_src,
    const float* __restrict__ a_dst, float* __restrict__ ssrc, float* __restrict__ sdst) {
  const int wave = threadIdx.x >> 6, lane = threadIdx.x & 63;
  const int row = blockIdx.x * 4 + wave;
  if (row >= N_NODES) return;
  const ushort4 hv = *(const ushort4*)(hp + (size_t)row * 256 + lane * 4);
  float h0 = bf2f(hv.x), h1 = bf2f(hv.y), h2 = bf2f(hv.z), h3 = bf2f(hv.w);
  float s0 = h0 * a_src[lane],       d0 = h0 * a_dst[lane];
  float s1 = h1 * a_src[64 + lane],  d1 = h1 * a_dst[64 + lane];
  float s2 = h2 * a_src[128 + lane], d2 = h2 * a_dst[128 + lane];
  float s3 = h3 * a_src[192 + lane], d3 = h3 * a_dst[192 + lane];
#pragma unroll
  for (int off = 1; off < 64; off <<= 1) {
    s0 += __shfl_xor(s0, off); d0 += __shfl_xor(d0, off);
    s1 += __shfl_xor(s1, off); d1 += __shfl_xor(d1, off);
    s2 += __shfl_xor(s2, off); d2 += __shfl_xor(d2, off);
    s3 += __shfl_xor(s3, off); d3 += __shfl_xor(d3, off);
  }
  if (lane == 0) {
    float4 sv = { s0, s1, s2, s3 };
    float4 dv = { d0, d1, d2, d3 };
    *(float4*)(ssrc + row * 4) = sv;
    *(float4*)(sdst + row * 4) = dv;
  }
}

// ---------------------------------------------------------------------------
// CSR build
// ---------------------------------------------------------------------------
static __device__ __forceinline__ void edge_sd(const int* ei, int e, int& src, int& dst) {
  if (e < N_EDGES) { src = ei[e]; dst = ei[N_EDGES + e]; }
  else             { src = dst = e - N_EDGES; }
}

__global__ __launch_bounds__(256) void deg_count_int(const int* __restrict__ ei, int* __restrict__ degi) {
  int e = blockIdx.x * 256 + threadIdx.x;
  if (e >= ETOT) return;
  int dst = (e < N_EDGES) ? ei[N_EDGES + e] : (e - N_EDGES);
  atomicAdd(&degi[dst], 1);
}

__global__ __launch_bounds__(256) void scan1(const int* __restrict__ degi,
                                             int* __restrict__ partial, int* __restrict__ bsum) {
  __shared__ int sm[256];
  int i = blockIdx.x * 256 + threadIdx.x;
  int v = (i < N_NODES) ? degi[i] : 0;
  sm[threadIdx.x] = v;
  __syncthreads();
#pragma unroll
  for (int off = 1; off < 256; off <<= 1) {
    int t = (threadIdx.x >= off) ? sm[threadIdx.x - off] : 0;
    __syncthreads();
    sm[threadIdx.x] += t;
    __syncthreads();
  }
  if (i < N_NODES) partial[i] = sm[threadIdx.x] - v;
  if (threadIdx.x == 255) bsum[blockIdx.x] = sm[255];
}

__global__ __launch_bounds__(256) void scan2(int* __restrict__ bsum) {
  __shared__ int sm[256];
  int v = (threadIdx.x < SCAN_BLOCKS) ? bsum[threadIdx.x] : 0;
  sm[threadIdx.x] = v;
  __syncthreads();
#pragma unroll
  for (int off = 1; off < 256; off <<= 1) {
    int t = (threadIdx.x >= off) ? sm[threadIdx.x - off] : 0;
    __syncthreads();
    sm[threadIdx.x] += t;
    __syncthreads();
  }
  if (threadIdx.x < SCAN_BLOCKS) bsum[threadIdx.x] = sm[threadIdx.x] - v;
}

__global__ __launch_bounds__(256) void scan3(int* __restrict__ rowstart, const int* __restrict__ bsum,
                                             int* __restrict__ cursor, const int* __restrict__ degi,
                                             float* __restrict__ dinv) {
  int i = blockIdx.x * 256 + threadIdx.x;
  if (i >= N_NODES) return;
  int r = rowstart[i] + bsum[blockIdx.x];
  rowstart[i] = r;
  cursor[i] = r;
  dinv[i] = rsqrtf(fmaxf((float)degi[i], 1.0f));
}

__global__ __launch_bounds__(256) void scatter_k(const int* __restrict__ ei,
                                                 int* __restrict__ cursor, int* __restrict__ csr) {
  int e = blockIdx.x * 256 + threadIdx.x;
  if (e >= ETOT) return;
  int src, dst; edge_sd(ei, e, src, dst);
  int pos = atomicAdd(&cursor[dst], 1);
  csr[pos] = src;
}

// ---------------------------------------------------------------------------
// GAT aggregations (gather over CSR, online softmax; logits bounded).
// 2-unrolled inner loops for memory-level parallelism.
// ---------------------------------------------------------------------------
__global__ __launch_bounds__(256) void gat_agg1_bf(
    const int* __restrict__ rowstart, const int* __restrict__ degi, const int* __restrict__ csr,
    const ushort* __restrict__ h, const float* __restrict__ ssrc, const float* __restrict__ sdst,
    float* __restrict__ outp) {
  int dst = blockIdx.x * 4 + (threadIdx.x >> 6);
  if (dst >= N_NODES) return;
  int lane = threadIdx.x & 63;
  int hh = lane >> 4;
  int rs = rowstart[dst], re = rs + degi[dst];
  float sd = sdst[dst * 4 + hh];
  float z = 0.f;
  float ax = 0.f, ay = 0.f, az = 0.f, aw = 0.f;
  int j = rs;
  for (; j + 1 < re; j += 2) {
    int s0 = csr[j], s1 = csr[j + 1];
    float e0 = ssrc[s0 * 4 + hh], e1 = ssrc[s1 * 4 + hh];
    const ushort4 hv0 = *(const ushort4*)(h + (size_t)s0 * 256 + lane * 4);
    const ushort4 hv1 = *(const ushort4*)(h + (size_t)s1 * 256 + lane * 4);
    float p0 = __expf(leaky(e0 + sd));
    float p1 = __expf(leaky(e1 + sd));
    z += p0 + p1;
    ax += p0 * bf2f(hv0.x) + p1 * bf2f(hv1.x);
    ay += p0 * bf2f(hv0.y) + p1 * bf2f(hv1.y);
    az += p0 * bf2f(hv0.z) + p1 * bf2f(hv1.z);
    aw += p0 * bf2f(hv0.w) + p1 * bf2f(hv1.w);
  }
  if (j < re) {
    int s0 = csr[j];
    float p0 = __expf(leaky(ssrc[s0 * 4 + hh] + sd));
    const ushort4 hv0 = *(const ushort4*)(h + (size_t)s0 * 256 + lane * 4);
    z += p0;
    ax += p0 * bf2f(hv0.x); ay += p0 * bf2f(hv0.y);
    az += p0 * bf2f(hv0.z); aw += p0 * bf2f(hv0.w);
  }
  float inv = 1.f / z;
  float4 o = { ax * inv, ay * inv, az * inv, aw * inv };
  *(float4*)(outp + (size_t)dst * 256 + lane * 4) = o;
}

// layer-2 aggregation over PERMUTED h2 (hp[row][c*4+h]); one ushort4/lane/edge
__global__ __launch_bounds__(256) void gat_agg2_perm(
    const int* __restrict__ rowstart, const int* __restrict__ degi, const int* __restrict__ csr,
    const ushort* __restrict__ hp, const float* __restrict__ ssrc, const float* __restrict__ sdst,
    float* __restrict__ outp) {
  int dst = blockIdx.x * 4 + (threadIdx.x >> 6);
  if (dst >= N_NODES) return;
  int lane = threadIdx.x & 63;
  int rs = rowstart[dst], re = rs + degi[dst];
  const float4 sd = *(const float4*)(sdst + dst * 4);
  float z0 = 0.f, z1 = 0.f, z2 = 0.f, z3 = 0.f;
  float a0 = 0.f, a1 = 0.f, a2 = 0.f, a3 = 0.f;
  int j = rs;
  for (; j + 1 < re; j += 2) {
    int s0 = csr[j], s1 = csr[j + 1];
    const float4 ss0 = *(const float4*)(ssrc + s0 * 4);
    const float4 ss1 = *(const float4*)(ssrc + s1 * 4);
    const ushort4 hv0 = *(const ushort4*)(hp + (size_t)s0 * 256 + lane * 4);
    const ushort4 hv1 = *(const ushort4*)(hp + (size_t)s1 * 256 + lane * 4);
    float p00 = __expf(leaky(ss0.x + sd.x)), p10 = __expf(leaky(ss1.x + sd.x));
    float p01 = __expf(leaky(ss0.y + sd.y)), p11 = __expf(leaky(ss1.y + sd.y));
    float p02 = __expf(leaky(ss0.z + sd.z)), p12 = __expf(leaky(ss1.z + sd.z));
    float p03 = __expf(leaky(ss0.w + sd.w)), p13 = __expf(leaky(ss1.w + sd.w));
    z0 += p00 + p10; z1 += p01 + p11; z2 += p02 + p12; z3 += p03 + p13;
    a0 += p00 * bf2f(hv0.x) + p10 * bf2f(hv1.x);
    a1 += p01 * bf2f(hv0.y) + p11 * bf2f(hv1.y);
    a2 += p02 * bf2f(hv0.z) + p12 * bf2f(hv1.z);
    a3 += p03 * bf2f(hv0.w) + p13 * bf2f(hv1.w);
  }
  if (j < re) {
    int s0 = csr[j];
    const float4 ss0 = *(const float4*)(ssrc + s0 * 4);
    const ushort4 hv0 = *(const ushort4*)(hp + (size_t)s0 * 256 + lane * 4);
    float p00 = __expf(leaky(ss0.x + sd.x));
    float p01 = __expf(leaky(ss0.y + sd.y));
    float p02 = __expf(leaky(ss0.z + sd.z));
    float p03 = __expf(leaky(ss0.w + sd.w));
    z0 += p00; z1 += p01; z2 += p02; z3 += p03;
    a0 += p00 * bf2f(hv0.x); a1 += p01 * bf2f(hv0.y);
    a2 += p02 * bf2f(hv0.z); a3 += p03 * bf2f(hv0.w);
  }
  outp[(size_t)dst * 64 + lane] = 0.25f * (a0 / z0 + a1 / z1 + a2 / z2 + a3 / z3);
}

// GCN layer-1 aggregation + bias + ReLU; bf16 in (g1), bf16 out
__global__ __launch_bounds__(256) void gcn_agg_relu_bf(
    const int* __restrict__ rowstart, const int* __restrict__ degi, const int* __restrict__ csr,
    const ushort* __restrict__ g, const float* __restrict__ dinv, const float* __restrict__ bias,
    ushort* __restrict__ outp) {
  int dst = blockIdx.x * 4 + (threadIdx.x >> 6);
  if (dst >= N_NODES) return;
  int lane = threadIdx.x & 63;
  int rs = rowstart[dst], re = rs + degi[dst];
  float acc = 0.f;
  int j = rs;
  for (; j + 1 < re; j += 2) {
    int s0 = csr[j], s1 = csr[j + 1];
    float d0 = dinv[s0], d1 = dinv[s1];
    float v0 = bf2f(g[(size_t)s0 * 64 + lane]);
    float v1 = bf2f(g[(size_t)s1 * 64 + lane]);
    acc += d0 * v0 + d1 * v1;
  }
  if (j < re) {
    int s0 = csr[j];
    acc += dinv[s0] * bf2f(g[(size_t)s0 * 64 + lane]);
  }
  float v = acc * dinv[dst] + bias[lane];
  outp[(size_t)dst * 64 + lane] = f2bf(fmaxf(v, 0.f));
}

// GCN layer-2 aggregation (bf16 g2) + bias, fused with drift-weighted combine
__global__ __launch_bounds__(256) void gcn_agg_fuse_bf(
    const int* __restrict__ rowstart, const int* __restrict__ degi, const int* __restrict__ csr,
    const ushort* __restrict__ g2, const float* __restrict__ dinv, const float* __restrict__ bg2,
    const float* __restrict__ hgat, const float* __restrict__ b2, const float* __restrict__ dw,
    float* __restrict__ outp) {
  int dst = blockIdx.x * 4 + (threadIdx.x >> 6);
  if (dst >= N_NODES) return;
  int lane = threadIdx.x & 63;
  int rs = rowstart[dst], re = rs + degi[dst];
  float acc = 0.f;
  int j = rs;
  for (; j + 1 < re; j += 2) {
    int s0 = csr[j], s1 = csr[j + 1];
    float d0 = dinv[s0], d1 = dinv[s1];
    float v0 = bf2f(g2[(size_t)s0 * 64 + lane]);
    float v1 = bf2f(g2[(size_t)s1 * 64 + lane]);
    acc += d0 * v0 + d1 * v1;
  }
  if (j < re) {
    int s0 = csr[j];
    acc += dinv[s0] * bf2f(g2[(size_t)s0 * 64 + lane]);
  }
  float w = dw[0];
  float gcn = acc * dinv[dst] + bg2[lane];
  float gat = hgat[(size_t)dst * 64 + lane] + b2[lane];
  outp[(size_t)dst * 64 + lane] = w * gat + (1.f - w) * gcn;
}

// ---------------------------------------------------------------------------
// BatchNorm
// ---------------------------------------------------------------------------
__global__ __launch_bounds__(256) void bn_stats(
    const float* __restrict__ x, float* __restrict__ sum, float* __restrict__ sumsq) {
  int f = threadIdx.x;
  int r0 = blockIdx.x * 64;
  int rend = min(r0 + 64, N_NODES);
  float s = 0.f, s2 = 0.f;
  for (int r = r0; r < rend; ++r) {
    float v = x[(size_t)r * 256 + f];
    s += v; s2 += v * v;
  }
  atomicAdd(&sum[f], s);
  atomicAdd(&sumsq[f], s2);
}

// BN + ELU, emits bf16 directly (A operand of the W2 MFMA GEMM)
__global__ __launch_bounds__(256) void bn_apply_bf16(
    const float* __restrict__ x, const float* __restrict__ sum, const float* __restrict__ sumsq,
    const float* __restrict__ gamma, const float* __restrict__ beta, ushort* __restrict__ o) {
  size_t i = (size_t)blockIdx.x * 256 + threadIdx.x;
  if (i >= (size_t)N_NODES * 256) return;
  int f = (int)(i & 255);
  const float invN = 1.0f / N_NODES;
  float mu = sum[f] * invN;
  float var = sumsq[f] * invN - mu * mu;
  float v = (x[i] - mu) * rsqrtf(var + EPS) * gamma[f] + beta[f];
  float e = v > 0.f ? v : expf(v) - 1.0f;
  o[i] = f2bf(e);
}

extern "C" void kernel_launch(void* const* d_in, const int* in_sizes, int n_in,
                              void* d_out, int out_size, void* d_ws, size_t ws_size,
                              hipStream_t stream) {
  const float* x     = (const float*)d_in[0];
  const int*   ei    = (const int*)d_in[1];
  const float* dw    = (const float*)d_in[2];
  const float* W1    = (const float*)d_in[3];
  const float* as1   = (const float*)d_in[4];
  const float* ad1   = (const float*)d_in[5];
  // d_in[6] = b1: cancels through BatchNorm
  const float* gamma = (const float*)d_in[7];
  const float* beta  = (const float*)d_in[8];
  const float* W2    = (const float*)d_in[9];
  const float* as2   = (const float*)d_in[10];
  const float* ad2   = (const float*)d_in[11];
  const float* b2    = (const float*)d_in[12];
  const float* Wg1   = (const float*)d_in[13];
  const float* bg1   = (const float*)d_in[14];
  const float* Wg2   = (const float*)d_in[15];
  const float* bg2   = (const float*)d_in[16];
  float* out = (float*)d_out;

  char* p = (char*)d_ws;
  size_t off = 0;
  auto alloc = [&](size_t bytes) {
    char* r = p + off;
    off = (off + bytes + 255) & ~(size_t)255;
    return r;
  };
  float*  bufB  = (float*)alloc((size_t)N_NODES * 256 * 4);   // agg1 fp32; later overlaid by h2 perm bf16
  float*  bufC  = (float*)alloc((size_t)N_NODES * 64 * 4);    // h_gat fp32
  ushort* xbf   = (ushort*)alloc((size_t)M_PAD * 128 * 2);    // x bf16 (GEMM-A, padded)
  ushort* R1    = (ushort*)alloc((size_t)M_PAD * 256 * 2);    // h1bf, then hbn bf16 (GEMM-A, padded)
  ushort* g1bf  = (ushort*)alloc((size_t)N_NODES * 64 * 2);
  ushort* gbf   = (ushort*)alloc((size_t)M_PAD * 64 * 2);     // relu(g) bf16 (GEMM-A, padded)
  ushort* g2bf  = (ushort*)alloc((size_t)N_NODES * 64 * 2);
  ushort* w1t   = (ushort*)alloc((size_t)256 * 128 * 2);
  ushort* w2t   = (ushort*)alloc((size_t)256 * 256 * 2);
  ushort* wg1t  = (ushort*)alloc((size_t)64 * 128 * 2);
  ushort* wg2t  = (ushort*)alloc((size_t)64 * 64 * 2);
  float*  ssrc1 = (float*)alloc((size_t)N_NODES * 4 * 4);
  float*  sdst1 = (float*)alloc((size_t)N_NODES * 4 * 4);
  float*  ssrc2 = (float*)alloc((size_t)N_NODES * 4 * 4);
  float*  sdst2 = (float*)alloc((size_t)N_NODES * 4 * 4);
  int*    degi  = (int*)alloc((size_t)N_NODES * 4);
  int*    rowst = (int*)alloc((size_t)N_NODES * 4);
  int*    cursor= (int*)alloc((size_t)N_NODES * 4);
  int*    bsum  = (int*)alloc(SCAN_BLOCKS * 4);
  float*  dinv  = (float*)alloc((size_t)N_NODES * 4);
  int*    csr   = (int*)alloc((size_t)ETOT * 4);
  float*  bnsum = (float*)alloc(256 * 4);
  float*  bnsq  = (float*)alloc(256 * 4);
  ushort* h2p   = (ushort*)bufB;   // overlay: bufB fp32 dead after bn_apply; holds permuted h2

  const dim3 blk(256);
  const int egrid = (ETOT + 255) / 256;
  const int ngrid = 12500;

  hipMemsetAsync(degi, 0, (size_t)N_NODES * 4, stream);
  hipMemsetAsync(bnsum, 0, 256 * 4, stream);
  hipMemsetAsync(bnsq, 0, 256 * 4, stream);
  // zero GEMM-A pad rows (row-guarded writes never touch them afterwards)
  hipMemsetAsync(R1 + (size_t)N_NODES * 256, 0, (size_t)(M_PAD - N_NODES) * 256 * 2, stream);
  hipMemsetAsync(gbf + (size_t)N_NODES * 64, 0, (size_t)(M_PAD - N_NODES) * 64 * 2, stream);

  // ---- CSR build + bf16 prep ----
  deg_count_int<<<egrid, blk, 0, stream>>>(ei, degi);
  scan1<<<SCAN_BLOCKS, blk, 0, stream>>>(degi, rowst, bsum);
  scan2<<<1, blk, 0, stream>>>(bsum);
  scan3<<<SCAN_BLOCKS, blk, 0, stream>>>(rowst, bsum, cursor, degi, dinv);
  scatter_k<<<egrid, blk, 0, stream>>>(ei, cursor, csr);
  cast_x_bf16<<<(M_PAD * 32 + 255) / 256, blk, 0, stream>>>(x, xbf);
  tcast_w<<<(128 * 256 + 255) / 256, blk, 0, stream>>>(W1, w1t, 128, 256);
  tcast_w<<<(256 * 256 + 255) / 256, blk, 0, stream>>>(W2, w2t, 256, 256);
  tcast_w<<<(128 * 64 + 255) / 256, blk, 0, stream>>>(Wg1, wg1t, 128, 64);
  tcast_w<<<(64 * 64 + 255) / 256, blk, 0, stream>>>(Wg2, wg2t, 64, 64);

  // ---- GEMMs off x (xbf dead after these) ----
  gemm_bf16<128, true, false><<<dim3(782, 4), blk, 0, stream>>>(xbf, w1t, R1, N_NODES, 256);    // h1
  gemm_bf16<128, true, false><<<dim3(782, 1), blk, 0, stream>>>(xbf, wg1t, g1bf, N_NODES, 64);  // g1

  // ---- GAT layer 1 ----
  attn_scores_bf<<<ngrid, blk, 0, stream>>>(R1, as1, ad1, ssrc1, sdst1);
  gat_agg1_bf<<<ngrid, blk, 0, stream>>>(rowst, degi, csr, R1, ssrc1, sdst1, bufB);

  // ---- GCN layer 1 (independent) ----
  gcn_agg_relu_bf<<<ngrid, blk, 0, stream>>>(rowst, degi, csr, g1bf, dinv, bg1, gbf);
  gemm_bf16<64, true, false><<<dim3(782, 1), blk, 0, stream>>>(gbf, wg2t, g2bf, N_NODES, 64);   // g2

  // ---- BatchNorm + ELU -> hbn bf16 (reuses R1; h1bf dead) ----
  bn_stats<<<(N_NODES + 63) / 64, blk, 0, stream>>>(bufB, bnsum, bnsq);
  bn_apply_bf16<<<(int)(((size_t)N_NODES * 256 + 255) / 256), blk, 0, stream>>>(
      bufB, bnsum, bnsq, gamma, beta, R1);

  // ---- GAT layer 2: h2 written head-interleaved (h2p overlays dead bufB) ----
  gemm_bf16<256, true, true><<<dim3(782, 4), blk, 0, stream>>>(R1, w2t, h2p, N_NODES, 256);     // h2 perm
  attn_scores_perm<<<ngrid, blk, 0, stream>>>(h2p, as2, ad2, ssrc2, sdst2);
  gat_agg2_perm<<<ngrid, blk, 0, stream>>>(rowst, degi, csr, h2p, ssrc2, sdst2, bufC);

  // ---- GCN layer 2 + drift-weighted fusion ----
  gcn_agg_fuse_bf<<<ngrid, blk, 0, stream>>>(rowst, degi, csr, g2bf, dinv, bg2, bufC, b2, dw, out);
}